// Round 1
// baseline (716.425 us; speedup 1.0000x reference)
//
#include <hip/hip_runtime.h>

#define CH 128           // feature channels (CIN == COUT == 128)
#define GEMM_BM 128      // rows per GEMM block
#define GEMM_KK 16       // K chunk
#define LDSPAD 132       // 128 + 4 pad

// ---------------------------------------------------------------- setup ----

__global__ void hist_k(const int* __restrict__ dst, int* __restrict__ deg, int E) {
    int e = blockIdx.x * blockDim.x + threadIdx.x;
    if (e < E) atomicAdd(&deg[dst[e]], 1);
}

// block-local exclusive scan (1024 elems/block), Hillis-Steele in LDS
__global__ __launch_bounds__(1024) void scan_partial_k(const int* __restrict__ deg,
                                                       int* __restrict__ rowptr,
                                                       int* __restrict__ bsum, int N) {
    __shared__ int sm[1024];
    int t = threadIdx.x;
    int i = blockIdx.x * 1024 + t;
    int v = (i < N) ? deg[i] : 0;
    sm[t] = v;
    __syncthreads();
    int x = v;
    for (int off = 1; off < 1024; off <<= 1) {
        int y = (t >= off) ? sm[t - off] : 0;
        __syncthreads();
        x += y;
        sm[t] = x;
        __syncthreads();
    }
    if (i < N) rowptr[i] = x - v;          // block-local exclusive
    if (t == 1023) bsum[blockIdx.x] = x;   // block total
}

__global__ void scan_bsums_k(const int* __restrict__ bsum, int* __restrict__ bofs,
                             int nb, int* __restrict__ rowptr, int N) {
    if (threadIdx.x == 0 && blockIdx.x == 0) {
        int run = 0;
        for (int b = 0; b < nb; ++b) { bofs[b] = run; run += bsum[b]; }
        rowptr[N] = run;   // == E
    }
}

__global__ __launch_bounds__(1024) void scan_add_k(int* __restrict__ rowptr,
                                                   const int* __restrict__ bofs, int N) {
    int i = blockIdx.x * 1024 + threadIdx.x;
    if (i < N) rowptr[i] += bofs[blockIdx.x];
}

__global__ void dis_k(const int* __restrict__ deg, float* __restrict__ dis, int N) {
    int n = blockIdx.x * blockDim.x + threadIdx.x;
    if (n < N) {
        int d = deg[n];
        dis[n] = (d > 0) ? rsqrtf((float)d) : 0.f;
    }
}

__global__ void fill_k(const int* __restrict__ src, const int* __restrict__ dst,
                       const int* __restrict__ rowptr, int* __restrict__ fill,
                       const float* __restrict__ dis, int* __restrict__ csrc,
                       float* __restrict__ cw, int E) {
    int e = blockIdx.x * blockDim.x + threadIdx.x;
    if (e >= E) return;
    int s = src[e], d = dst[e];
    int pos = rowptr[d] + atomicAdd(&fill[d], 1);
    csrc[pos] = s;
    cw[pos] = -dis[s] * dis[d];
}

// ---------------------------------------------------------------- prop -----
// out[n] = alpha * sum_{e in CSR[n]} w[e]*xin[src[e]]  + beta * other[n]
// one wave per node, float2 per lane (128 ch = 64 lanes * 2)

__global__ __launch_bounds__(256) void prop_k(const float2* __restrict__ xin,
                                              const int* __restrict__ rowptr,
                                              const int* __restrict__ csrc,
                                              const float* __restrict__ cw,
                                              const float2* __restrict__ other,
                                              float alpha, float beta,
                                              float2* __restrict__ out, int M) {
    int n = blockIdx.x * 4 + (threadIdx.x >> 6);
    if (n >= M) return;
    int lane = threadIdx.x & 63;
    int e0 = rowptr[n], e1 = rowptr[n + 1];
    float ax = 0.f, ay = 0.f, bx = 0.f, by = 0.f;
    int e = e0;
    for (; e + 2 <= e1; e += 2) {
        int s0 = csrc[e], s1 = csrc[e + 1];
        float w0 = cw[e], w1 = cw[e + 1];
        float2 v0 = xin[(size_t)s0 * 64 + lane];
        float2 v1 = xin[(size_t)s1 * 64 + lane];
        ax = fmaf(w0, v0.x, ax); ay = fmaf(w0, v0.y, ay);
        bx = fmaf(w1, v1.x, bx); by = fmaf(w1, v1.y, by);
    }
    if (e < e1) {
        int s0 = csrc[e]; float w0 = cw[e];
        float2 v0 = xin[(size_t)s0 * 64 + lane];
        ax = fmaf(w0, v0.x, ax); ay = fmaf(w0, v0.y, ay);
    }
    float rx = alpha * (ax + bx), ry = alpha * (ay + by);
    if (beta != 0.f) {
        float2 o = other[(size_t)n * 64 + lane];
        rx = fmaf(beta, o.x, rx); ry = fmaf(beta, o.y, ry);
    }
    out[(size_t)n * 64 + lane] = make_float2(rx, ry);
}

// ---------------------------------------------------------------- GEMM -----
// C[m0:m0+128][0:128] (+)= sum_p A_p @ W_p (+ bias)
// W pieces stacked contiguously: W + p*128*128, row-major [k][c]
// 256 threads, 8x8 register tile per thread.

__global__ __launch_bounds__(256) void gemm_k(const float* __restrict__ A0,
                                              const float* __restrict__ A1,
                                              const float* __restrict__ A2,
                                              const float* __restrict__ W,
                                              const float* __restrict__ bias,
                                              float* __restrict__ C,
                                              int M, int nP, int accum) {
    __shared__ float As[GEMM_KK][LDSPAD];  // transposed A tile [k][row]
    __shared__ float Bs[GEMM_KK][LDSPAD];  // B tile [k][col]
    int t = threadIdx.x;
    int m0 = blockIdx.x * GEMM_BM;
    float acc[8][8];
    #pragma unroll
    for (int i = 0; i < 8; ++i)
        #pragma unroll
        for (int j = 0; j < 8; ++j) acc[i][j] = 0.f;

    const float* Aps[3] = {A0, A1, A2};
    int tr = t >> 4, tc = t & 15;   // 16x16 thread grid

    for (int p = 0; p < nP; ++p) {
        const float* A = Aps[p];
        const float* Wp = W + (size_t)p * CH * CH;
        for (int k0 = 0; k0 < CH; k0 += GEMM_KK) {
            // stage A: 128 rows x 16 k  (512 float4 loads, transposed store)
            #pragma unroll
            for (int i = 0; i < 2; ++i) {
                int lin = t + i * 256;       // 0..511
                int row = lin >> 2;          // 0..127
                int kq  = lin & 3;           // 0..3
                float4 v = make_float4(0.f, 0.f, 0.f, 0.f);
                if (m0 + row < M)
                    v = *(const float4*)&A[(size_t)(m0 + row) * CH + k0 + 4 * kq];
                As[4 * kq + 0][row] = v.x;
                As[4 * kq + 1][row] = v.y;
                As[4 * kq + 2][row] = v.z;
                As[4 * kq + 3][row] = v.w;
            }
            // stage B: 16 k x 128 cols
            #pragma unroll
            for (int i = 0; i < 2; ++i) {
                int lin = t + i * 256;       // 0..511
                int kr = lin >> 5;           // 0..15
                int cq = lin & 31;           // 0..31
                *(float4*)&Bs[kr][4 * cq] =
                    *(const float4*)&Wp[(size_t)(k0 + kr) * CH + 4 * cq];
            }
            __syncthreads();
            #pragma unroll
            for (int kk = 0; kk < GEMM_KK; ++kk) {
                float a[8], b[8];
                *(float4*)&a[0] = *(const float4*)&As[kk][8 * tr];
                *(float4*)&a[4] = *(const float4*)&As[kk][8 * tr + 4];
                *(float4*)&b[0] = *(const float4*)&Bs[kk][8 * tc];
                *(float4*)&b[4] = *(const float4*)&Bs[kk][8 * tc + 4];
                #pragma unroll
                for (int i = 0; i < 8; ++i)
                    #pragma unroll
                    for (int j = 0; j < 8; ++j)
                        acc[i][j] = fmaf(a[i], b[j], acc[i][j]);
            }
            __syncthreads();
        }
    }

    // epilogue
    float bj[8];
    #pragma unroll
    for (int j = 0; j < 8; ++j) bj[j] = bias ? bias[8 * tc + j] : 0.f;
    for (int i = 0; i < 8; ++i) {
        int m = m0 + 8 * tr + i;
        if (m >= M) continue;
        float4* Crow = (float4*)&C[(size_t)m * CH + 8 * tc];
        float4 v0 = make_float4(acc[i][0] + bj[0], acc[i][1] + bj[1],
                                acc[i][2] + bj[2], acc[i][3] + bj[3]);
        float4 v1 = make_float4(acc[i][4] + bj[4], acc[i][5] + bj[5],
                                acc[i][6] + bj[6], acc[i][7] + bj[7]);
        if (accum) {
            float4 c0 = Crow[0], c1 = Crow[1];
            v0.x += c0.x; v0.y += c0.y; v0.z += c0.z; v0.w += c0.w;
            v1.x += c1.x; v1.y += c1.y; v1.z += c1.z; v1.w += c1.w;
        }
        Crow[0] = v0; Crow[1] = v1;
    }
}

// ---------------------------------------------------------------- BN -------

__global__ __launch_bounds__(256) void bnstats_k(const float* __restrict__ h,
                                                 float* __restrict__ sums, int M) {
    __shared__ float ls[512];
    int c = threadIdx.x & 127, half = threadIdx.x >> 7;
    float s = 0.f, q = 0.f;
    for (int r = blockIdx.x * 2 + half; r < M; r += gridDim.x * 2) {
        float v = h[(size_t)r * CH + c];
        s += v; q = fmaf(v, v, q);
    }
    ls[threadIdx.x] = s;
    ls[256 + threadIdx.x] = q;
    __syncthreads();
    if (half == 0) {
        atomicAdd(&sums[c],       s + ls[128 + c]);
        atomicAdd(&sums[128 + c], q + ls[256 + 128 + c]);
    }
}

__global__ void bncoef_k(const float* __restrict__ sums, const float* __restrict__ gamma,
                         const float* __restrict__ beta, float* __restrict__ coef,
                         float invM) {
    int c = threadIdx.x;  // 128 threads
    float m   = sums[c] * invM;
    float var = fmaxf(sums[128 + c] * invM - m * m, 0.f);
    float sc  = gamma[c] * rsqrtf(var + 1e-5f);
    coef[c]       = sc;
    coef[128 + c] = beta[c] - m * sc;
}

__global__ __launch_bounds__(256) void bnapply_k(float* __restrict__ h,
                                                 const float* __restrict__ coef, int M) {
    int total = M * (CH / 4);
    for (int idx = blockIdx.x * blockDim.x + threadIdx.x; idx < total;
         idx += gridDim.x * blockDim.x) {
        int cq = (idx & 31) * 4;
        float4 v = ((float4*)h)[idx];
        v.x = fmaxf(fmaf(v.x, coef[cq + 0], coef[128 + cq + 0]), 0.f);
        v.y = fmaxf(fmaf(v.y, coef[cq + 1], coef[128 + cq + 1]), 0.f);
        v.z = fmaxf(fmaf(v.z, coef[cq + 2], coef[128 + cq + 2]), 0.f);
        v.w = fmaxf(fmaf(v.w, coef[cq + 3], coef[128 + cq + 3]), 0.f);
        ((float4*)h)[idx] = v;
    }
}

// ---------------------------------------------------------------- launch ---

extern "C" void kernel_launch(void* const* d_in, const int* in_sizes, int n_in,
                              void* d_out, int out_size, void* d_ws, size_t ws_size,
                              hipStream_t stream) {
    const float* x      = (const float*)d_in[0];
    const int*   ei     = (const int*)d_in[1];
    const float* w1     = (const float*)d_in[2];
    const float* b1     = (const float*)d_in[3];
    const float* w2     = (const float*)d_in[4];
    const float* b2     = (const float*)d_in[5];
    const float* w3     = (const float*)d_in[6];
    const float* b3     = (const float*)d_in[7];
    const float* gamma1 = (const float*)d_in[8];
    const float* beta1  = (const float*)d_in[9];
    const float* gamma2 = (const float*)d_in[10];
    const float* beta2  = (const float*)d_in[11];
    float* out = (float*)d_out;

    const int M = in_sizes[0] / CH;   // 50000 nodes
    const int E = in_sizes[1] / 2;    // 600000 edges
    const int* srcp = ei;
    const int* dstp = ei + E;

    // workspace layout (~108 MB total)
    size_t off = 0;
    auto alloc = [&](size_t bytes) {
        void* p = (char*)d_ws + off;
        off += (bytes + 255) & ~(size_t)255;
        return p;
    };
    float* P0     = (float*)alloc((size_t)M * CH * 4);
    float* P1     = (float*)alloc((size_t)M * CH * 4);
    float* P2     = (float*)alloc((size_t)M * CH * 4);
    float* P3     = (float*)alloc((size_t)M * CH * 4);
    int*   csrc   = (int*)  alloc((size_t)E * 4);
    float* cw     = (float*)alloc((size_t)E * 4);
    int*   degi   = (int*)  alloc((size_t)M * 4);
    int*   rowptr = (int*)  alloc((size_t)(M + 1) * 4);
    int*   fil    = (int*)  alloc((size_t)M * 4);
    float* dis    = (float*)alloc((size_t)M * 4);
    int*   bsum   = (int*)  alloc(4096);
    int*   bofs   = (int*)  alloc(4096);
    float* bnsums = (float*)alloc(1024);
    float* coef   = (float*)alloc(1024);
    (void)ws_size; (void)n_in; (void)out_size;

    const int nb = (M + 1023) / 1024;
    const int gb = (M + GEMM_BM - 1) / GEMM_BM;
    const int pgrid = (M + 3) / 4;

    // ---- graph setup: degree -> rowptr -> CSR
    hipMemsetAsync(degi, 0, (size_t)M * 4, stream);
    hipMemsetAsync(fil,  0, (size_t)M * 4, stream);
    hist_k<<<(E + 255) / 256, 256, 0, stream>>>(dstp, degi, E);
    scan_partial_k<<<nb, 1024, 0, stream>>>(degi, rowptr, bsum, M);
    scan_bsums_k<<<1, 64, 0, stream>>>(bsum, bofs, nb, rowptr, M);
    scan_add_k<<<nb, 1024, 0, stream>>>(rowptr, bofs, M);
    dis_k<<<(M + 255) / 256, 256, 0, stream>>>(degi, dis, M);
    fill_k<<<(E + 255) / 256, 256, 0, stream>>>(srcp, dstp, rowptr, fil, dis, csrc, cw, E);

    // ---- layer 1: h1 = x @ W1 + b1 ; BN+ReLU  -> P0
    gemm_k<<<gb, 256, 0, stream>>>(x, nullptr, nullptr, w1, b1, P0, M, 1, 0);
    hipMemsetAsync(bnsums, 0, 1024, stream);
    bnstats_k<<<256, 256, 0, stream>>>(P0, bnsums, M);
    bncoef_k<<<1, 128, 0, stream>>>(bnsums, gamma1, beta1, coef, 1.f / (float)M);
    bnapply_k<<<2048, 256, 0, stream>>>(P0, coef, M);

    // ---- layer 2 (K=3): Tx0=P0, Tx1=P1, Tx2=P2 ; out -> P3
    prop_k<<<pgrid, 256, 0, stream>>>((const float2*)P0, rowptr, csrc, cw,
                                      (const float2*)P0, 1.f, 0.f, (float2*)P1, M);
    prop_k<<<pgrid, 256, 0, stream>>>((const float2*)P1, rowptr, csrc, cw,
                                      (const float2*)P0, 2.f, -1.f, (float2*)P2, M);
    gemm_k<<<gb, 256, 0, stream>>>(P0, P1, P2, w2, b2, P3, M, 3, 0);
    hipMemsetAsync(bnsums, 0, 1024, stream);
    bnstats_k<<<256, 256, 0, stream>>>(P3, bnsums, M);
    bncoef_k<<<1, 128, 0, stream>>>(bnsums, gamma2, beta2, coef, 1.f / (float)M);
    bnapply_k<<<2048, 256, 0, stream>>>(P3, coef, M);

    // ---- layer 3 (K=5): Tx0=P3, U1=P0, U2=P1, then U3=P2, U4=P3(reused)
    prop_k<<<pgrid, 256, 0, stream>>>((const float2*)P3, rowptr, csrc, cw,
                                      (const float2*)P3, 1.f, 0.f, (float2*)P0, M);
    prop_k<<<pgrid, 256, 0, stream>>>((const float2*)P0, rowptr, csrc, cw,
                                      (const float2*)P3, 2.f, -1.f, (float2*)P1, M);
    gemm_k<<<gb, 256, 0, stream>>>(P3, P0, P1, w3, b3, out, M, 3, 0);        // k=0..2
    prop_k<<<pgrid, 256, 0, stream>>>((const float2*)P1, rowptr, csrc, cw,
                                      (const float2*)P0, 2.f, -1.f, (float2*)P2, M);
    prop_k<<<pgrid, 256, 0, stream>>>((const float2*)P2, rowptr, csrc, cw,
                                      (const float2*)P1, 2.f, -1.f, (float2*)P3, M);
    gemm_k<<<gb, 256, 0, stream>>>(P2, P3, nullptr, w3 + (size_t)3 * CH * CH,
                                   nullptr, out, M, 2, 1);                   // k=3..4 accum
}

// Round 2
// 578.689 us; speedup vs baseline: 1.2380x; 1.2380x over previous
//
#include <hip/hip_runtime.h>

#define CH 128           // feature channels (CIN == COUT == 128)
#define GEMM_BM 128      // rows per GEMM block
#define KSTEP 32         // K chunk per MFMA stage
#define LDP 40           // LDS row pitch in bf16 elems (80B -> conflict-free-ish)

typedef __attribute__((ext_vector_type(8))) short bf16x8;
typedef __attribute__((ext_vector_type(4))) float f32x4;

static __device__ __forceinline__ unsigned short f2bf(float f) {
    unsigned int u = __float_as_uint(f);
    unsigned int r = (u + 0x7FFFu + ((u >> 16) & 1u)) >> 16;
    return (unsigned short)r;
}

// ---------------------------------------------------------------- setup ----

__global__ void hist_k(const int* __restrict__ dst, int* __restrict__ deg, int E) {
    int e = blockIdx.x * blockDim.x + threadIdx.x;
    if (e < E) atomicAdd(&deg[dst[e]], 1);
}

// block-local exclusive scan (1024 elems/block), Hillis-Steele in LDS
__global__ __launch_bounds__(1024) void scan_partial_k(const int* __restrict__ deg,
                                                       int* __restrict__ rowptr,
                                                       int* __restrict__ bsum, int N) {
    __shared__ int sm[1024];
    int t = threadIdx.x;
    int i = blockIdx.x * 1024 + t;
    int v = (i < N) ? deg[i] : 0;
    sm[t] = v;
    __syncthreads();
    int x = v;
    for (int off = 1; off < 1024; off <<= 1) {
        int y = (t >= off) ? sm[t - off] : 0;
        __syncthreads();
        x += y;
        sm[t] = x;
        __syncthreads();
    }
    if (i < N) rowptr[i] = x - v;          // block-local exclusive
    if (t == 1023) bsum[blockIdx.x] = x;   // block total
}

__global__ void scan_bsums_k(const int* __restrict__ bsum, int* __restrict__ bofs,
                             int nb, int* __restrict__ rowptr, int N) {
    if (threadIdx.x == 0 && blockIdx.x == 0) {
        int run = 0;
        for (int b = 0; b < nb; ++b) { bofs[b] = run; run += bsum[b]; }
        rowptr[N] = run;   // == E
    }
}

__global__ __launch_bounds__(1024) void scan_add_k(int* __restrict__ rowptr,
                                                   const int* __restrict__ bofs, int N) {
    int i = blockIdx.x * 1024 + threadIdx.x;
    if (i < N) rowptr[i] += bofs[blockIdx.x];
}

__global__ void dis_k(const int* __restrict__ deg, float* __restrict__ dis, int N) {
    int n = blockIdx.x * blockDim.x + threadIdx.x;
    if (n < N) {
        int d = deg[n];
        dis[n] = (d > 0) ? rsqrtf((float)d) : 0.f;
    }
}

__global__ void fill_k(const int* __restrict__ src, const int* __restrict__ dst,
                       const int* __restrict__ rowptr, int* __restrict__ fill,
                       const float* __restrict__ dis, int* __restrict__ csrc,
                       float* __restrict__ cw, int E) {
    int e = blockIdx.x * blockDim.x + threadIdx.x;
    if (e >= E) return;
    int s = src[e], d = dst[e];
    int pos = rowptr[d] + atomicAdd(&fill[d], 1);
    csrc[pos] = s;
    cw[pos] = -dis[s] * dis[d];
}

// weight convert: fp32 [p][k][c] -> bf16 transposed [p][c][k]
__global__ void wconv_k(const float* __restrict__ W, short* __restrict__ Wt, int total) {
    int idx = blockIdx.x * blockDim.x + threadIdx.x;
    if (idx >= total) return;
    int p = idx >> 14;
    int k = (idx >> 7) & 127;
    int c = idx & 127;
    Wt[(p << 14) + (c << 7) + k] = (short)f2bf(W[idx]);
}

// ---------------------------------------------------------------- prop -----
// out[n] = alpha * sum_{e in CSR[n]} w[e]*xin[src[e]]  + beta * other[n]
// one wave per node, float2 per lane (128 ch = 64 lanes * 2)

__global__ __launch_bounds__(256) void prop_k(const float2* __restrict__ xin,
                                              const int* __restrict__ rowptr,
                                              const int* __restrict__ csrc,
                                              const float* __restrict__ cw,
                                              const float2* __restrict__ other,
                                              float alpha, float beta,
                                              float2* __restrict__ out, int M) {
    int n = blockIdx.x * 4 + (threadIdx.x >> 6);
    if (n >= M) return;
    int lane = threadIdx.x & 63;
    int e0 = rowptr[n], e1 = rowptr[n + 1];
    float ax = 0.f, ay = 0.f, bx = 0.f, by = 0.f;
    int e = e0;
    for (; e + 2 <= e1; e += 2) {
        int s0 = csrc[e], s1 = csrc[e + 1];
        float w0 = cw[e], w1 = cw[e + 1];
        float2 v0 = xin[(size_t)s0 * 64 + lane];
        float2 v1 = xin[(size_t)s1 * 64 + lane];
        ax = fmaf(w0, v0.x, ax); ay = fmaf(w0, v0.y, ay);
        bx = fmaf(w1, v1.x, bx); by = fmaf(w1, v1.y, by);
    }
    if (e < e1) {
        int s0 = csrc[e]; float w0 = cw[e];
        float2 v0 = xin[(size_t)s0 * 64 + lane];
        ax = fmaf(w0, v0.x, ax); ay = fmaf(w0, v0.y, ay);
    }
    float rx = alpha * (ax + bx), ry = alpha * (ay + by);
    if (beta != 0.f) {
        float2 o = other[(size_t)n * 64 + lane];
        rx = fmaf(beta, o.x, rx); ry = fmaf(beta, o.y, ry);
    }
    out[(size_t)n * 64 + lane] = make_float2(rx, ry);
}

// ---------------------------------------------------------------- GEMM -----
// MFMA bf16 GEMM: C[m0:m0+128][0:128] (+)= sum_p A_p @ W_p (+ bias)
// A_p: fp32 [M][128], converted to bf16 during LDS staging.
// Wt:  bf16 transposed [piece][col][k], pieces stacked.
// 256 threads = 4 waves; wave w owns rows 32w..32w+31 (2 m-frags x 8 n-frags).

__global__ __launch_bounds__(256) void gemm_k(const float* __restrict__ A0,
                                              const float* __restrict__ A1,
                                              const float* __restrict__ A2,
                                              const short* __restrict__ Wt,
                                              const float* __restrict__ bias,
                                              float* __restrict__ C,
                                              int M, int nP, int accum) {
    __shared__ short As[128 * LDP];   // [row][k] padded
    __shared__ short Bs[128 * LDP];   // [col][k] padded
    int t = threadIdx.x;
    int m0 = blockIdx.x * GEMM_BM;
    int wave = t >> 6;
    int lane = t & 63;
    int lh = lane & 15;        // fragment row/col within 16
    int kq = lane >> 4;        // k-group 0..3

    f32x4 acc[2][8];
    #pragma unroll
    for (int i = 0; i < 2; ++i)
        #pragma unroll
        for (int j = 0; j < 8; ++j) acc[i][j] = (f32x4){0.f, 0.f, 0.f, 0.f};

    const float* Aps[3] = {A0, A1, A2};
    int srow = t >> 1;                 // staging row/col 0..127
    int skh  = (t & 1) << 4;           // staging k offset 0 or 16

    for (int p = 0; p < nP; ++p) {
        const float* A = Aps[p];
        const short* Wp = Wt + ((size_t)p << 14);
        for (int k0 = 0; k0 < CH; k0 += KSTEP) {
            __syncthreads();   // previous tile fully consumed
            // ---- stage A: 128 rows x 32 k, fp32 -> bf16
            {
                float4 v0, v1, v2, v3;
                if (m0 + srow < M) {
                    const float4* src = (const float4*)&A[(size_t)(m0 + srow) * CH + k0 + skh];
                    v0 = src[0]; v1 = src[1]; v2 = src[2]; v3 = src[3];
                } else {
                    v0 = v1 = v2 = v3 = make_float4(0.f, 0.f, 0.f, 0.f);
                }
                bf16x8 lo, hi;
                lo[0] = (short)f2bf(v0.x); lo[1] = (short)f2bf(v0.y);
                lo[2] = (short)f2bf(v0.z); lo[3] = (short)f2bf(v0.w);
                lo[4] = (short)f2bf(v1.x); lo[5] = (short)f2bf(v1.y);
                lo[6] = (short)f2bf(v1.z); lo[7] = (short)f2bf(v1.w);
                hi[0] = (short)f2bf(v2.x); hi[1] = (short)f2bf(v2.y);
                hi[2] = (short)f2bf(v2.z); hi[3] = (short)f2bf(v2.w);
                hi[4] = (short)f2bf(v3.x); hi[5] = (short)f2bf(v3.y);
                hi[6] = (short)f2bf(v3.z); hi[7] = (short)f2bf(v3.w);
                *(bf16x8*)&As[srow * LDP + skh]     = lo;
                *(bf16x8*)&As[srow * LDP + skh + 8] = hi;
            }
            // ---- stage B: 128 cols x 32 k, already bf16 [col][k]
            {
                const bf16x8* src = (const bf16x8*)&Wp[(srow << 7) + k0 + skh];
                *(bf16x8*)&Bs[srow * LDP + skh]     = src[0];
                *(bf16x8*)&Bs[srow * LDP + skh + 8] = src[1];
            }
            __syncthreads();
            // ---- fragments + MFMA
            bf16x8 af[2], bfr[8];
            #pragma unroll
            for (int fm = 0; fm < 2; ++fm)
                af[fm] = *(const bf16x8*)&As[(wave * 32 + fm * 16 + lh) * LDP + kq * 8];
            #pragma unroll
            for (int fn = 0; fn < 8; ++fn)
                bfr[fn] = *(const bf16x8*)&Bs[(fn * 16 + lh) * LDP + kq * 8];
            #pragma unroll
            for (int fm = 0; fm < 2; ++fm)
                #pragma unroll
                for (int fn = 0; fn < 8; ++fn)
                    acc[fm][fn] = __builtin_amdgcn_mfma_f32_16x16x32_bf16(
                        af[fm], bfr[fn], acc[fm][fn], 0, 0, 0);
        }
    }

    // ---- epilogue: row = m0 + wave*32 + fm*16 + kq*4 + j, col = fn*16 + lh
    #pragma unroll
    for (int fm = 0; fm < 2; ++fm) {
        #pragma unroll
        for (int j = 0; j < 4; ++j) {
            int m = m0 + wave * 32 + fm * 16 + kq * 4 + j;
            if (m >= M) continue;
            float* Crow = &C[(size_t)m * CH];
            #pragma unroll
            for (int fn = 0; fn < 8; ++fn) {
                int col = fn * 16 + lh;
                float v = acc[fm][fn][j];
                if (bias) v += bias[col];
                if (accum) v += Crow[col];
                Crow[col] = v;
            }
        }
    }
}

// ---------------------------------------------------------------- BN -------

__global__ __launch_bounds__(256) void bnstats_k(const float* __restrict__ h,
                                                 float* __restrict__ sums, int M) {
    __shared__ float ls[512];
    int c = threadIdx.x & 127, half = threadIdx.x >> 7;
    float s = 0.f, q = 0.f;
    for (int r = blockIdx.x * 2 + half; r < M; r += gridDim.x * 2) {
        float v = h[(size_t)r * CH + c];
        s += v; q = fmaf(v, v, q);
    }
    ls[threadIdx.x] = s;
    ls[256 + threadIdx.x] = q;
    __syncthreads();
    if (half == 0) {
        atomicAdd(&sums[c],       s + ls[128 + c]);
        atomicAdd(&sums[128 + c], q + ls[256 + 128 + c]);
    }
}

__global__ void bncoef_k(const float* __restrict__ sums, const float* __restrict__ gamma,
                         const float* __restrict__ beta, float* __restrict__ coef,
                         float invM) {
    int c = threadIdx.x;  // 128 threads
    float m   = sums[c] * invM;
    float var = fmaxf(sums[128 + c] * invM - m * m, 0.f);
    float sc  = gamma[c] * rsqrtf(var + 1e-5f);
    coef[c]       = sc;
    coef[128 + c] = beta[c] - m * sc;
}

__global__ __launch_bounds__(256) void bnapply_k(float* __restrict__ h,
                                                 const float* __restrict__ coef, int M) {
    int total = M * (CH / 4);
    for (int idx = blockIdx.x * blockDim.x + threadIdx.x; idx < total;
         idx += gridDim.x * blockDim.x) {
        int cq = (idx & 31) * 4;
        float4 v = ((float4*)h)[idx];
        v.x = fmaxf(fmaf(v.x, coef[cq + 0], coef[128 + cq + 0]), 0.f);
        v.y = fmaxf(fmaf(v.y, coef[cq + 1], coef[128 + cq + 1]), 0.f);
        v.z = fmaxf(fmaf(v.z, coef[cq + 2], coef[128 + cq + 2]), 0.f);
        v.w = fmaxf(fmaf(v.w, coef[cq + 3], coef[128 + cq + 3]), 0.f);
        ((float4*)h)[idx] = v;
    }
}

// ---------------------------------------------------------------- launch ---

extern "C" void kernel_launch(void* const* d_in, const int* in_sizes, int n_in,
                              void* d_out, int out_size, void* d_ws, size_t ws_size,
                              hipStream_t stream) {
    const float* x      = (const float*)d_in[0];
    const int*   ei     = (const int*)d_in[1];
    const float* w1     = (const float*)d_in[2];
    const float* b1     = (const float*)d_in[3];
    const float* w2     = (const float*)d_in[4];
    const float* b2     = (const float*)d_in[5];
    const float* w3     = (const float*)d_in[6];
    const float* b3     = (const float*)d_in[7];
    const float* gamma1 = (const float*)d_in[8];
    const float* beta1  = (const float*)d_in[9];
    const float* gamma2 = (const float*)d_in[10];
    const float* beta2  = (const float*)d_in[11];
    float* out = (float*)d_out;

    const int M = in_sizes[0] / CH;   // 50000 nodes
    const int E = in_sizes[1] / 2;    // 600000 edges
    const int* srcp = ei;
    const int* dstp = ei + E;

    // workspace layout (~108 MB total)
    size_t off = 0;
    auto alloc = [&](size_t bytes) {
        void* p = (char*)d_ws + off;
        off += (bytes + 255) & ~(size_t)255;
        return p;
    };
    float* P0     = (float*)alloc((size_t)M * CH * 4);
    float* P1     = (float*)alloc((size_t)M * CH * 4);
    float* P2     = (float*)alloc((size_t)M * CH * 4);
    float* P3     = (float*)alloc((size_t)M * CH * 4);
    int*   csrc   = (int*)  alloc((size_t)E * 4);
    float* cw     = (float*)alloc((size_t)E * 4);
    int*   degi   = (int*)  alloc((size_t)M * 4);
    int*   rowptr = (int*)  alloc((size_t)(M + 1) * 4);
    int*   fil    = (int*)  alloc((size_t)M * 4);
    float* dis    = (float*)alloc((size_t)M * 4);
    int*   bsum   = (int*)  alloc(4096);
    int*   bofs   = (int*)  alloc(4096);
    float* bnsums = (float*)alloc(1024);
    float* coef   = (float*)alloc(1024);
    short* Wt1    = (short*)alloc((size_t)1 * CH * CH * 2);
    short* Wt2    = (short*)alloc((size_t)3 * CH * CH * 2);
    short* Wt3    = (short*)alloc((size_t)5 * CH * CH * 2);
    (void)ws_size; (void)n_in; (void)out_size;

    const int nb = (M + 1023) / 1024;
    const int gb = (M + GEMM_BM - 1) / GEMM_BM;
    const int pgrid = (M + 3) / 4;

    // ---- graph setup: degree -> rowptr -> CSR ; weight conversion
    hipMemsetAsync(degi, 0, (size_t)M * 4, stream);
    hipMemsetAsync(fil,  0, (size_t)M * 4, stream);
    hist_k<<<(E + 255) / 256, 256, 0, stream>>>(dstp, degi, E);
    scan_partial_k<<<nb, 1024, 0, stream>>>(degi, rowptr, bsum, M);
    scan_bsums_k<<<1, 64, 0, stream>>>(bsum, bofs, nb, rowptr, M);
    scan_add_k<<<nb, 1024, 0, stream>>>(rowptr, bofs, M);
    dis_k<<<(M + 255) / 256, 256, 0, stream>>>(degi, dis, M);
    fill_k<<<(E + 255) / 256, 256, 0, stream>>>(srcp, dstp, rowptr, fil, dis, csrc, cw, E);
    wconv_k<<<(1 * 16384 + 255) / 256, 256, 0, stream>>>(w1, Wt1, 1 * 16384);
    wconv_k<<<(3 * 16384 + 255) / 256, 256, 0, stream>>>(w2, Wt2, 3 * 16384);
    wconv_k<<<(5 * 16384 + 255) / 256, 256, 0, stream>>>(w3, Wt3, 5 * 16384);

    // ---- layer 1: h1 = x @ W1 + b1 ; BN+ReLU  -> P0
    gemm_k<<<gb, 256, 0, stream>>>(x, nullptr, nullptr, Wt1, b1, P0, M, 1, 0);
    hipMemsetAsync(bnsums, 0, 1024, stream);
    bnstats_k<<<256, 256, 0, stream>>>(P0, bnsums, M);
    bncoef_k<<<1, 128, 0, stream>>>(bnsums, gamma1, beta1, coef, 1.f / (float)M);
    bnapply_k<<<2048, 256, 0, stream>>>(P0, coef, M);

    // ---- layer 2 (K=3): Tx0=P0, Tx1=P1, Tx2=P2 ; out -> P3
    prop_k<<<pgrid, 256, 0, stream>>>((const float2*)P0, rowptr, csrc, cw,
                                      (const float2*)P0, 1.f, 0.f, (float2*)P1, M);
    prop_k<<<pgrid, 256, 0, stream>>>((const float2*)P1, rowptr, csrc, cw,
                                      (const float2*)P0, 2.f, -1.f, (float2*)P2, M);
    gemm_k<<<gb, 256, 0, stream>>>(P0, P1, P2, Wt2, b2, P3, M, 3, 0);
    hipMemsetAsync(bnsums, 0, 1024, stream);
    bnstats_k<<<256, 256, 0, stream>>>(P3, bnsums, M);
    bncoef_k<<<1, 128, 0, stream>>>(bnsums, gamma2, beta2, coef, 1.f / (float)M);
    bnapply_k<<<2048, 256, 0, stream>>>(P3, coef, M);

    // ---- layer 3 (K=5): Tx0=P3, U1=P0, U2=P1, then U3=P2, U4=P3(reused)
    prop_k<<<pgrid, 256, 0, stream>>>((const float2*)P3, rowptr, csrc, cw,
                                      (const float2*)P3, 1.f, 0.f, (float2*)P0, M);
    prop_k<<<pgrid, 256, 0, stream>>>((const float2*)P0, rowptr, csrc, cw,
                                      (const float2*)P3, 2.f, -1.f, (float2*)P1, M);
    gemm_k<<<gb, 256, 0, stream>>>(P3, P0, P1, Wt3, b3, out, M, 3, 0);        // k=0..2
    prop_k<<<pgrid, 256, 0, stream>>>((const float2*)P1, rowptr, csrc, cw,
                                      (const float2*)P0, 2.f, -1.f, (float2*)P2, M);
    prop_k<<<pgrid, 256, 0, stream>>>((const float2*)P2, rowptr, csrc, cw,
                                      (const float2*)P1, 2.f, -1.f, (float2*)P3, M);
    gemm_k<<<gb, 256, 0, stream>>>(P2, P3, nullptr, Wt3 + (size_t)3 * CH * CH,
                                   nullptr, out, M, 2, 1);                   // k=3..4 accum
}

// Round 3
// 513.635 us; speedup vs baseline: 1.3948x; 1.1267x over previous
//
#include <hip/hip_runtime.h>

#define CH 128           // feature channels (CIN == COUT == 128)
#define GEMM_BM 128      // rows per GEMM block
#define KSTEP 32         // K chunk per MFMA stage
#define LDP 40           // LDS row pitch in bf16 elems (80B -> conflict-free-ish)

typedef __attribute__((ext_vector_type(8))) short bf16x8;
typedef __attribute__((ext_vector_type(4))) float f32x4;

static __device__ __forceinline__ unsigned short f2bf(float f) {
    unsigned int u = __float_as_uint(f);
    unsigned int r = (u + 0x7FFFu + ((u >> 16) & 1u)) >> 16;
    return (unsigned short)r;
}
static __device__ __forceinline__ float bflo(unsigned int v) {
    return __uint_as_float(v << 16);
}
static __device__ __forceinline__ float bfhi(unsigned int v) {
    return __uint_as_float(v & 0xffff0000u);
}

// ---------------------------------------------------------------- setup ----

__global__ void hist_k(const int* __restrict__ dst, int* __restrict__ deg, int E) {
    int e = blockIdx.x * blockDim.x + threadIdx.x;
    if (e < E) atomicAdd(&deg[dst[e]], 1);
}

__global__ __launch_bounds__(1024) void scan_partial_k(const int* __restrict__ deg,
                                                       int* __restrict__ rowptr,
                                                       int* __restrict__ bsum, int N) {
    __shared__ int sm[1024];
    int t = threadIdx.x;
    int i = blockIdx.x * 1024 + t;
    int v = (i < N) ? deg[i] : 0;
    sm[t] = v;
    __syncthreads();
    int x = v;
    for (int off = 1; off < 1024; off <<= 1) {
        int y = (t >= off) ? sm[t - off] : 0;
        __syncthreads();
        x += y;
        sm[t] = x;
        __syncthreads();
    }
    if (i < N) rowptr[i] = x - v;          // block-local exclusive
    if (t == 1023) bsum[blockIdx.x] = x;   // block total
}

__global__ void scan_bsums_k(const int* __restrict__ bsum, int* __restrict__ bofs,
                             int nb, int* __restrict__ rowptr, int N) {
    if (threadIdx.x == 0 && blockIdx.x == 0) {
        int run = 0;
        for (int b = 0; b < nb; ++b) { bofs[b] = run; run += bsum[b]; }
        rowptr[N] = run;   // == E
    }
}

__global__ __launch_bounds__(1024) void scan_add_k(int* __restrict__ rowptr,
                                                   const int* __restrict__ bofs, int N) {
    int i = blockIdx.x * 1024 + threadIdx.x;
    if (i < N) rowptr[i] += bofs[blockIdx.x];
}

__global__ void dis_k(const int* __restrict__ deg, float* __restrict__ dis, int N) {
    int n = blockIdx.x * blockDim.x + threadIdx.x;
    if (n < N) {
        int d = deg[n];
        dis[n] = (d > 0) ? rsqrtf((float)d) : 0.f;
    }
}

__global__ void fill_k(const int* __restrict__ src, const int* __restrict__ dst,
                       const int* __restrict__ rowptr, int* __restrict__ fill,
                       const float* __restrict__ dis, int* __restrict__ csrc,
                       float* __restrict__ cw, int E) {
    int e = blockIdx.x * blockDim.x + threadIdx.x;
    if (e >= E) return;
    int s = src[e], d = dst[e];
    int pos = rowptr[d] + atomicAdd(&fill[d], 1);
    csrc[pos] = s;
    cw[pos] = -dis[s] * dis[d];
}

// weight convert: fp32 [p][k][c] -> bf16 transposed [p][c][k]
__global__ void wconv_k(const float* __restrict__ W, short* __restrict__ Wt, int total) {
    int idx = blockIdx.x * blockDim.x + threadIdx.x;
    if (idx >= total) return;
    int p = idx >> 14;
    int k = (idx >> 7) & 127;
    int c = idx & 127;
    Wt[(p << 14) + (c << 7) + k] = (short)f2bf(W[idx]);
}

// ---------------------------------------------------------------- prop -----
// bf16 features: row = 128 bf16 = 64 uints. One wave per node, 1 uint/lane.
// out[n] = bf16( alpha * sum_e w[e]*xin[src[e]] + beta * other[n] )

__global__ __launch_bounds__(256) void prop_k(const unsigned int* __restrict__ xin,
                                              const int* __restrict__ rowptr,
                                              const int* __restrict__ csrc,
                                              const float* __restrict__ cw,
                                              const unsigned int* __restrict__ other,
                                              float alpha, float beta,
                                              unsigned int* __restrict__ out, int M) {
    int n = blockIdx.x * 4 + (threadIdx.x >> 6);
    if (n >= M) return;
    int lane = threadIdx.x & 63;
    int e0 = rowptr[n], e1 = rowptr[n + 1];
    float ax = 0.f, ay = 0.f, bx = 0.f, by = 0.f;
    int e = e0;
    for (; e + 2 <= e1; e += 2) {
        int s0 = csrc[e], s1 = csrc[e + 1];
        float w0 = cw[e], w1 = cw[e + 1];
        unsigned int v0 = xin[(size_t)s0 * 64 + lane];
        unsigned int v1 = xin[(size_t)s1 * 64 + lane];
        ax = fmaf(w0, bflo(v0), ax); ay = fmaf(w0, bfhi(v0), ay);
        bx = fmaf(w1, bflo(v1), bx); by = fmaf(w1, bfhi(v1), by);
    }
    if (e < e1) {
        int s0 = csrc[e]; float w0 = cw[e];
        unsigned int v0 = xin[(size_t)s0 * 64 + lane];
        ax = fmaf(w0, bflo(v0), ax); ay = fmaf(w0, bfhi(v0), ay);
    }
    float rx = alpha * (ax + bx), ry = alpha * (ay + by);
    if (beta != 0.f) {
        unsigned int o = other[(size_t)n * 64 + lane];
        rx = fmaf(beta, bflo(o), rx);
        ry = fmaf(beta, bfhi(o), ry);
    }
    out[(size_t)n * 64 + lane] =
        (unsigned int)f2bf(rx) | ((unsigned int)f2bf(ry) << 16);
}

// ---------------------------------------------------------------- GEMM -----
// MFMA bf16 GEMM: C[m0:m0+128][0:128] (+)= sum_p A_p @ W_p (+ bias)
// ABF=false: A_p fp32 [M][128], converted to bf16 during staging (layer 1).
// ABF=true:  A_p bf16 [M][128], staged directly.
// Wt: bf16 transposed [piece][col][k]. 4 waves; wave owns rows 32w..32w+31.

template<bool ABF>
__global__ __launch_bounds__(256) void gemm_k(const void* __restrict__ A0_,
                                              const void* __restrict__ A1_,
                                              const void* __restrict__ A2_,
                                              const short* __restrict__ Wt,
                                              const float* __restrict__ bias,
                                              float* __restrict__ C,
                                              int M, int nP, int accum) {
    __shared__ short As[128 * LDP];   // [row][k] padded
    __shared__ short Bs[128 * LDP];   // [col][k] padded
    int t = threadIdx.x;
    int m0 = blockIdx.x * GEMM_BM;
    int wave = t >> 6;
    int lane = t & 63;
    int lh = lane & 15;        // fragment row/col within 16
    int kq = lane >> 4;        // k-group 0..3

    f32x4 acc[2][8];
    #pragma unroll
    for (int i = 0; i < 2; ++i)
        #pragma unroll
        for (int j = 0; j < 8; ++j) acc[i][j] = (f32x4){0.f, 0.f, 0.f, 0.f};

    const void* Aps[3] = {A0_, A1_, A2_};
    int srow = t >> 1;                 // staging row/col 0..127
    int skh  = (t & 1) << 4;           // staging k offset 0 or 16

    for (int p = 0; p < nP; ++p) {
        const short* Wp = Wt + ((size_t)p << 14);
        for (int k0 = 0; k0 < CH; k0 += KSTEP) {
            __syncthreads();   // previous tile fully consumed
            // ---- stage A: 128 rows x 32 k
            if (ABF) {
                const unsigned short* A = (const unsigned short*)Aps[p];
                bf16x8 lo = {0,0,0,0,0,0,0,0}, hi = {0,0,0,0,0,0,0,0};
                if (m0 + srow < M) {
                    const bf16x8* src = (const bf16x8*)&A[(size_t)(m0 + srow) * CH + k0 + skh];
                    lo = src[0]; hi = src[1];
                }
                *(bf16x8*)&As[srow * LDP + skh]     = lo;
                *(bf16x8*)&As[srow * LDP + skh + 8] = hi;
            } else {
                const float* A = (const float*)Aps[p];
                float4 v0, v1, v2, v3;
                if (m0 + srow < M) {
                    const float4* src = (const float4*)&A[(size_t)(m0 + srow) * CH + k0 + skh];
                    v0 = src[0]; v1 = src[1]; v2 = src[2]; v3 = src[3];
                } else {
                    v0 = v1 = v2 = v3 = make_float4(0.f, 0.f, 0.f, 0.f);
                }
                bf16x8 lo, hi;
                lo[0] = (short)f2bf(v0.x); lo[1] = (short)f2bf(v0.y);
                lo[2] = (short)f2bf(v0.z); lo[3] = (short)f2bf(v0.w);
                lo[4] = (short)f2bf(v1.x); lo[5] = (short)f2bf(v1.y);
                lo[6] = (short)f2bf(v1.z); lo[7] = (short)f2bf(v1.w);
                hi[0] = (short)f2bf(v2.x); hi[1] = (short)f2bf(v2.y);
                hi[2] = (short)f2bf(v2.z); hi[3] = (short)f2bf(v2.w);
                hi[4] = (short)f2bf(v3.x); hi[5] = (short)f2bf(v3.y);
                hi[6] = (short)f2bf(v3.z); hi[7] = (short)f2bf(v3.w);
                *(bf16x8*)&As[srow * LDP + skh]     = lo;
                *(bf16x8*)&As[srow * LDP + skh + 8] = hi;
            }
            // ---- stage B: 128 cols x 32 k, already bf16 [col][k]
            {
                const bf16x8* src = (const bf16x8*)&Wp[(srow << 7) + k0 + skh];
                *(bf16x8*)&Bs[srow * LDP + skh]     = src[0];
                *(bf16x8*)&Bs[srow * LDP + skh + 8] = src[1];
            }
            __syncthreads();
            // ---- fragments + MFMA
            bf16x8 af[2], bfr[8];
            #pragma unroll
            for (int fm = 0; fm < 2; ++fm)
                af[fm] = *(const bf16x8*)&As[(wave * 32 + fm * 16 + lh) * LDP + kq * 8];
            #pragma unroll
            for (int fn = 0; fn < 8; ++fn)
                bfr[fn] = *(const bf16x8*)&Bs[(fn * 16 + lh) * LDP + kq * 8];
            #pragma unroll
            for (int fm = 0; fm < 2; ++fm)
                #pragma unroll
                for (int fn = 0; fn < 8; ++fn)
                    acc[fm][fn] = __builtin_amdgcn_mfma_f32_16x16x32_bf16(
                        af[fm], bfr[fn], acc[fm][fn], 0, 0, 0);
        }
    }

    // ---- epilogue: row = m0 + wave*32 + fm*16 + kq*4 + j, col = fn*16 + lh
    #pragma unroll
    for (int fm = 0; fm < 2; ++fm) {
        #pragma unroll
        for (int j = 0; j < 4; ++j) {
            int m = m0 + wave * 32 + fm * 16 + kq * 4 + j;
            if (m >= M) continue;
            float* Crow = &C[(size_t)m * CH];
            #pragma unroll
            for (int fn = 0; fn < 8; ++fn) {
                int col = fn * 16 + lh;
                float v = acc[fm][fn][j];
                if (bias) v += bias[col];
                if (accum) v += Crow[col];
                Crow[col] = v;
            }
        }
    }
}

// ---------------------------------------------------------------- BN -------

__global__ __launch_bounds__(256) void bnstats_k(const float* __restrict__ h,
                                                 float* __restrict__ sums, int M) {
    __shared__ float ls[512];
    int c = threadIdx.x & 127, half = threadIdx.x >> 7;
    float s = 0.f, q = 0.f;
    for (int r = blockIdx.x * 2 + half; r < M; r += gridDim.x * 2) {
        float v = h[(size_t)r * CH + c];
        s += v; q = fmaf(v, v, q);
    }
    ls[threadIdx.x] = s;
    ls[256 + threadIdx.x] = q;
    __syncthreads();
    if (half == 0) {
        atomicAdd(&sums[c],       s + ls[128 + c]);
        atomicAdd(&sums[128 + c], q + ls[256 + 128 + c]);
    }
}

__global__ void bncoef_k(const float* __restrict__ sums, const float* __restrict__ gamma,
                         const float* __restrict__ beta, float* __restrict__ coef,
                         float invM) {
    int c = threadIdx.x;  // 128 threads
    float m   = sums[c] * invM;
    float var = fmaxf(sums[128 + c] * invM - m * m, 0.f);
    float sc  = gamma[c] * rsqrtf(var + 1e-5f);
    coef[c]       = sc;
    coef[128 + c] = beta[c] - m * sc;
}

// apply BN + ReLU, fp32 in -> bf16 out (2 channels per thread)
__global__ __launch_bounds__(256) void bnapply_k(const float* __restrict__ h,
                                                 const float* __restrict__ coef,
                                                 unsigned int* __restrict__ outb, int M) {
    int total = M * 64;
    for (int idx = blockIdx.x * blockDim.x + threadIdx.x; idx < total;
         idx += gridDim.x * blockDim.x) {
        int c2 = (idx & 63) * 2;
        float2 v = ((const float2*)h)[idx];
        float a = fmaxf(fmaf(v.x, coef[c2 + 0], coef[128 + c2 + 0]), 0.f);
        float b = fmaxf(fmaf(v.y, coef[c2 + 1], coef[128 + c2 + 1]), 0.f);
        outb[idx] = (unsigned int)f2bf(a) | ((unsigned int)f2bf(b) << 16);
    }
}

// ---------------------------------------------------------------- launch ---

extern "C" void kernel_launch(void* const* d_in, const int* in_sizes, int n_in,
                              void* d_out, int out_size, void* d_ws, size_t ws_size,
                              hipStream_t stream) {
    const float* x      = (const float*)d_in[0];
    const int*   ei     = (const int*)d_in[1];
    const float* w1     = (const float*)d_in[2];
    const float* b1     = (const float*)d_in[3];
    const float* w2     = (const float*)d_in[4];
    const float* b2     = (const float*)d_in[5];
    const float* w3     = (const float*)d_in[6];
    const float* b3     = (const float*)d_in[7];
    const float* gamma1 = (const float*)d_in[8];
    const float* beta1  = (const float*)d_in[9];
    const float* gamma2 = (const float*)d_in[10];
    const float* beta2  = (const float*)d_in[11];
    float* out = (float*)d_out;

    const int M = in_sizes[0] / CH;   // 50000 nodes
    const int E = in_sizes[1] / 2;    // 600000 edges
    const int* srcp = ei;
    const int* dstp = ei + E;

    size_t off = 0;
    auto alloc = [&](size_t bytes) {
        void* p = (char*)d_ws + off;
        off += (bytes + 255) & ~(size_t)255;
        return p;
    };
    unsigned int* PB0 = (unsigned int*)alloc((size_t)M * CH * 2);  // bf16 feat
    unsigned int* PB1 = (unsigned int*)alloc((size_t)M * CH * 2);
    unsigned int* PB2 = (unsigned int*)alloc((size_t)M * CH * 2);
    unsigned int* PB3 = (unsigned int*)alloc((size_t)M * CH * 2);
    float* H      = (float*)alloc((size_t)M * CH * 4);             // fp32 pre-BN
    int*   csrc   = (int*)  alloc((size_t)E * 4);
    float* cw     = (float*)alloc((size_t)E * 4);
    int*   degi   = (int*)  alloc((size_t)M * 4);
    int*   rowptr = (int*)  alloc((size_t)(M + 1) * 4);
    int*   fil    = (int*)  alloc((size_t)M * 4);
    float* dis    = (float*)alloc((size_t)M * 4);
    int*   bsum   = (int*)  alloc(4096);
    int*   bofs   = (int*)  alloc(4096);
    float* bnsums = (float*)alloc(1024);
    float* coef   = (float*)alloc(1024);
    short* Wt1    = (short*)alloc((size_t)1 * CH * CH * 2);
    short* Wt2    = (short*)alloc((size_t)3 * CH * CH * 2);
    short* Wt3    = (short*)alloc((size_t)5 * CH * CH * 2);
    (void)ws_size; (void)n_in; (void)out_size;

    const int nb = (M + 1023) / 1024;
    const int gb = (M + GEMM_BM - 1) / GEMM_BM;
    const int pgrid = (M + 3) / 4;

    // ---- graph setup: degree -> rowptr -> CSR ; weight conversion
    hipMemsetAsync(degi, 0, (size_t)M * 4, stream);
    hipMemsetAsync(fil,  0, (size_t)M * 4, stream);
    hist_k<<<(E + 255) / 256, 256, 0, stream>>>(dstp, degi, E);
    scan_partial_k<<<nb, 1024, 0, stream>>>(degi, rowptr, bsum, M);
    scan_bsums_k<<<1, 64, 0, stream>>>(bsum, bofs, nb, rowptr, M);
    scan_add_k<<<nb, 1024, 0, stream>>>(rowptr, bofs, M);
    dis_k<<<(M + 255) / 256, 256, 0, stream>>>(degi, dis, M);
    fill_k<<<(E + 255) / 256, 256, 0, stream>>>(srcp, dstp, rowptr, fil, dis, csrc, cw, E);
    wconv_k<<<(1 * 16384 + 255) / 256, 256, 0, stream>>>(w1, Wt1, 1 * 16384);
    wconv_k<<<(3 * 16384 + 255) / 256, 256, 0, stream>>>(w2, Wt2, 3 * 16384);
    wconv_k<<<(5 * 16384 + 255) / 256, 256, 0, stream>>>(w3, Wt3, 5 * 16384);

    // ---- layer 1: H = x @ W1 + b1 ; BN+ReLU -> PB0 (bf16)
    gemm_k<false><<<gb, 256, 0, stream>>>(x, nullptr, nullptr, Wt1, b1, H, M, 1, 0);
    hipMemsetAsync(bnsums, 0, 1024, stream);
    bnstats_k<<<256, 256, 0, stream>>>(H, bnsums, M);
    bncoef_k<<<1, 128, 0, stream>>>(bnsums, gamma1, beta1, coef, 1.f / (float)M);
    bnapply_k<<<2048, 256, 0, stream>>>(H, coef, PB0, M);

    // ---- layer 2 (K=3): Tx0=PB0, Tx1=PB1, Tx2=PB2 ; H = sum ; BN+ReLU -> PB0
    prop_k<<<pgrid, 256, 0, stream>>>(PB0, rowptr, csrc, cw, PB0, 1.f, 0.f, PB1, M);
    prop_k<<<pgrid, 256, 0, stream>>>(PB1, rowptr, csrc, cw, PB0, 2.f, -1.f, PB2, M);
    gemm_k<true><<<gb, 256, 0, stream>>>(PB0, PB1, PB2, Wt2, b2, H, M, 3, 0);
    hipMemsetAsync(bnsums, 0, 1024, stream);
    bnstats_k<<<256, 256, 0, stream>>>(H, bnsums, M);
    bncoef_k<<<1, 128, 0, stream>>>(bnsums, gamma2, beta2, coef, 1.f / (float)M);
    bnapply_k<<<2048, 256, 0, stream>>>(H, coef, PB0, M);

    // ---- layer 3 (K=5): Tx0=PB0
    prop_k<<<pgrid, 256, 0, stream>>>(PB0, rowptr, csrc, cw, PB0, 1.f, 0.f, PB1, M);
    prop_k<<<pgrid, 256, 0, stream>>>(PB1, rowptr, csrc, cw, PB0, 2.f, -1.f, PB2, M);
    gemm_k<true><<<gb, 256, 0, stream>>>(PB0, PB1, PB2, Wt3, b3, out, M, 3, 0); // k=0..2
    prop_k<<<pgrid, 256, 0, stream>>>(PB2, rowptr, csrc, cw, PB1, 2.f, -1.f, PB3, M); // Tx3
    prop_k<<<pgrid, 256, 0, stream>>>(PB3, rowptr, csrc, cw, PB2, 2.f, -1.f, PB0, M); // Tx4
    gemm_k<true><<<gb, 256, 0, stream>>>(PB3, PB0, nullptr, Wt3 + (size_t)3 * CH * CH,
                                         nullptr, out, M, 2, 1);                // k=3..4 accum
}

// Round 4
// 458.391 us; speedup vs baseline: 1.5629x; 1.1205x over previous
//
#include <hip/hip_runtime.h>

#define CH 128           // feature channels (CIN == COUT == 128)
#define GEMM_BM 128      // rows per GEMM block
#define KSTEP 32         // K chunk per MFMA stage
#define LDP 40           // LDS row pitch in bf16 elems (80B -> conflict-free-ish)

typedef __attribute__((ext_vector_type(8))) short bf16x8;
typedef __attribute__((ext_vector_type(4))) float f32x4;

static __device__ __forceinline__ unsigned short f2bf(float f) {
    unsigned int u = __float_as_uint(f);
    unsigned int r = (u + 0x7FFFu + ((u >> 16) & 1u)) >> 16;
    return (unsigned short)r;
}
static __device__ __forceinline__ float bflo(unsigned int v) {
    return __uint_as_float(v << 16);
}
static __device__ __forceinline__ float bfhi(unsigned int v) {
    return __uint_as_float(v & 0xffff0000u);
}

// ---------------------------------------------------------------- setup ----

__global__ void hist_k(const int* __restrict__ dst, int* __restrict__ deg, int E) {
    int e = blockIdx.x * blockDim.x + threadIdx.x;
    if (e < E) atomicAdd(&deg[dst[e]], 1);
}

__global__ __launch_bounds__(1024) void scan_partial_k(const int* __restrict__ deg,
                                                       int* __restrict__ rowptr,
                                                       int* __restrict__ bsum, int N) {
    __shared__ int sm[1024];
    int t = threadIdx.x;
    int i = blockIdx.x * 1024 + t;
    int v = (i < N) ? deg[i] : 0;
    sm[t] = v;
    __syncthreads();
    int x = v;
    for (int off = 1; off < 1024; off <<= 1) {
        int y = (t >= off) ? sm[t - off] : 0;
        __syncthreads();
        x += y;
        sm[t] = x;
        __syncthreads();
    }
    if (i < N) rowptr[i] = x - v;          // block-local exclusive
    if (t == 1023) bsum[blockIdx.x] = x;   // block total
}

__global__ void scan_bsums_k(const int* __restrict__ bsum, int* __restrict__ bofs,
                             int nb, int* __restrict__ rowptr, int N) {
    if (threadIdx.x == 0 && blockIdx.x == 0) {
        int run = 0;
        for (int b = 0; b < nb; ++b) { bofs[b] = run; run += bsum[b]; }
        rowptr[N] = run;   // == E
    }
}

__global__ __launch_bounds__(1024) void scan_add_k(int* __restrict__ rowptr,
                                                   const int* __restrict__ bofs, int N) {
    int i = blockIdx.x * 1024 + threadIdx.x;
    if (i < N) rowptr[i] += bofs[blockIdx.x];
}

__global__ void dis_k(const int* __restrict__ deg, float* __restrict__ dis, int N) {
    int n = blockIdx.x * blockDim.x + threadIdx.x;
    if (n < N) {
        int d = deg[n];
        dis[n] = (d > 0) ? rsqrtf((float)d) : 0.f;
    }
}

// CSR fill: one packed 8B scatter per edge (halves write-allocate traffic
// vs two 4B scatters: each random write dirties a full 64B line)
__global__ void fill_k(const int* __restrict__ src, const int* __restrict__ dst,
                       const int* __restrict__ rowptr, int* __restrict__ fill,
                       const float* __restrict__ dis, int2* __restrict__ csw, int E) {
    int e = blockIdx.x * blockDim.x + threadIdx.x;
    if (e >= E) return;
    int s = src[e], d = dst[e];
    int pos = rowptr[d] + atomicAdd(&fill[d], 1);
    csw[pos] = make_int2(s, __float_as_int(-dis[s] * dis[d]));
}

// weight convert: fp32 [p][k][c] -> bf16 transposed [p][c][k]
__global__ void wconv_k(const float* __restrict__ W, short* __restrict__ Wt, int total) {
    int idx = blockIdx.x * blockDim.x + threadIdx.x;
    if (idx >= total) return;
    int p = idx >> 14;
    int k = (idx >> 7) & 127;
    int c = idx & 127;
    Wt[(p << 14) + (c << 7) + k] = (short)f2bf(W[idx]);
}

// ---------------------------------------------------------------- prop -----
// bf16 features: row = 128 bf16 = 64 uints. One wave per node, 1 uint/lane.
// 4-wide unroll: 4 gathers in flight per wave (latency-bound kernel).
// out[n] = bf16( alpha * sum_e w[e]*xin[src[e]] + beta * other[n] )

__global__ __launch_bounds__(256) void prop_k(const unsigned int* __restrict__ xin,
                                              const int* __restrict__ rowptr,
                                              const int2* __restrict__ csw,
                                              const unsigned int* __restrict__ other,
                                              float alpha, float beta,
                                              unsigned int* __restrict__ out, int M) {
    int n = blockIdx.x * 4 + (threadIdx.x >> 6);
    if (n >= M) return;
    int lane = threadIdx.x & 63;
    int e0 = rowptr[n], e1 = rowptr[n + 1];
    float ax = 0.f, ay = 0.f, bx = 0.f, by = 0.f;
    float cx = 0.f, cy = 0.f, dx = 0.f, dy = 0.f;
    int e = e0;
    for (; e + 4 <= e1; e += 4) {
        int2 p0 = csw[e], p1 = csw[e + 1], p2 = csw[e + 2], p3 = csw[e + 3];
        unsigned int v0 = xin[(size_t)p0.x * 64 + lane];
        unsigned int v1 = xin[(size_t)p1.x * 64 + lane];
        unsigned int v2 = xin[(size_t)p2.x * 64 + lane];
        unsigned int v3 = xin[(size_t)p3.x * 64 + lane];
        float w0 = __int_as_float(p0.y), w1 = __int_as_float(p1.y);
        float w2 = __int_as_float(p2.y), w3 = __int_as_float(p3.y);
        ax = fmaf(w0, bflo(v0), ax); ay = fmaf(w0, bfhi(v0), ay);
        bx = fmaf(w1, bflo(v1), bx); by = fmaf(w1, bfhi(v1), by);
        cx = fmaf(w2, bflo(v2), cx); cy = fmaf(w2, bfhi(v2), cy);
        dx = fmaf(w3, bflo(v3), dx); dy = fmaf(w3, bfhi(v3), dy);
    }
    for (; e < e1; ++e) {
        int2 p0 = csw[e];
        unsigned int v0 = xin[(size_t)p0.x * 64 + lane];
        float w0 = __int_as_float(p0.y);
        ax = fmaf(w0, bflo(v0), ax); ay = fmaf(w0, bfhi(v0), ay);
    }
    float rx = alpha * ((ax + bx) + (cx + dx));
    float ry = alpha * ((ay + by) + (cy + dy));
    if (beta != 0.f) {
        unsigned int o = other[(size_t)n * 64 + lane];
        rx = fmaf(beta, bflo(o), rx);
        ry = fmaf(beta, bfhi(o), ry);
    }
    out[(size_t)n * 64 + lane] =
        (unsigned int)f2bf(rx) | ((unsigned int)f2bf(ry) << 16);
}

// ---------------------------------------------------------------- GEMM -----
// MFMA bf16 GEMM: C[m0:m0+128][0:128] (+)= sum_p A_p @ W_p (+ bias)
// ABF=false: A_p fp32 [M][128], converted to bf16 during staging (layer 1).
// ABF=true:  A_p bf16 [M][128], staged directly.
// Wt: bf16 transposed [piece][col][k]. 4 waves; wave owns rows 32w..32w+31.

template<bool ABF>
__global__ __launch_bounds__(256) void gemm_k(const void* __restrict__ A0_,
                                              const void* __restrict__ A1_,
                                              const void* __restrict__ A2_,
                                              const short* __restrict__ Wt,
                                              const float* __restrict__ bias,
                                              float* __restrict__ C,
                                              int M, int nP, int accum) {
    __shared__ short As[128 * LDP];   // [row][k] padded
    __shared__ short Bs[128 * LDP];   // [col][k] padded
    int t = threadIdx.x;
    int m0 = blockIdx.x * GEMM_BM;
    int wave = t >> 6;
    int lane = t & 63;
    int lh = lane & 15;        // fragment row/col within 16
    int kq = lane >> 4;        // k-group 0..3

    f32x4 acc[2][8];
    #pragma unroll
    for (int i = 0; i < 2; ++i)
        #pragma unroll
        for (int j = 0; j < 8; ++j) acc[i][j] = (f32x4){0.f, 0.f, 0.f, 0.f};

    const void* Aps[3] = {A0_, A1_, A2_};
    int srow = t >> 1;                 // staging row/col 0..127
    int skh  = (t & 1) << 4;           // staging k offset 0 or 16

    for (int p = 0; p < nP; ++p) {
        const short* Wp = Wt + ((size_t)p << 14);
        for (int k0 = 0; k0 < CH; k0 += KSTEP) {
            __syncthreads();   // previous tile fully consumed
            // ---- stage A: 128 rows x 32 k
            if (ABF) {
                const unsigned short* A = (const unsigned short*)Aps[p];
                bf16x8 lo = {0,0,0,0,0,0,0,0}, hi = {0,0,0,0,0,0,0,0};
                if (m0 + srow < M) {
                    const bf16x8* src = (const bf16x8*)&A[(size_t)(m0 + srow) * CH + k0 + skh];
                    lo = src[0]; hi = src[1];
                }
                *(bf16x8*)&As[srow * LDP + skh]     = lo;
                *(bf16x8*)&As[srow * LDP + skh + 8] = hi;
            } else {
                const float* A = (const float*)Aps[p];
                float4 v0, v1, v2, v3;
                if (m0 + srow < M) {
                    const float4* src = (const float4*)&A[(size_t)(m0 + srow) * CH + k0 + skh];
                    v0 = src[0]; v1 = src[1]; v2 = src[2]; v3 = src[3];
                } else {
                    v0 = v1 = v2 = v3 = make_float4(0.f, 0.f, 0.f, 0.f);
                }
                bf16x8 lo, hi;
                lo[0] = (short)f2bf(v0.x); lo[1] = (short)f2bf(v0.y);
                lo[2] = (short)f2bf(v0.z); lo[3] = (short)f2bf(v0.w);
                lo[4] = (short)f2bf(v1.x); lo[5] = (short)f2bf(v1.y);
                lo[6] = (short)f2bf(v1.z); lo[7] = (short)f2bf(v1.w);
                hi[0] = (short)f2bf(v2.x); hi[1] = (short)f2bf(v2.y);
                hi[2] = (short)f2bf(v2.z); hi[3] = (short)f2bf(v2.w);
                hi[4] = (short)f2bf(v3.x); hi[5] = (short)f2bf(v3.y);
                hi[6] = (short)f2bf(v3.z); hi[7] = (short)f2bf(v3.w);
                *(bf16x8*)&As[srow * LDP + skh]     = lo;
                *(bf16x8*)&As[srow * LDP + skh + 8] = hi;
            }
            // ---- stage B: 128 cols x 32 k, already bf16 [col][k]
            {
                const bf16x8* src = (const bf16x8*)&Wp[(srow << 7) + k0 + skh];
                *(bf16x8*)&Bs[srow * LDP + skh]     = src[0];
                *(bf16x8*)&Bs[srow * LDP + skh + 8] = src[1];
            }
            __syncthreads();
            // ---- fragments + MFMA
            bf16x8 af[2], bfr[8];
            #pragma unroll
            for (int fm = 0; fm < 2; ++fm)
                af[fm] = *(const bf16x8*)&As[(wave * 32 + fm * 16 + lh) * LDP + kq * 8];
            #pragma unroll
            for (int fn = 0; fn < 8; ++fn)
                bfr[fn] = *(const bf16x8*)&Bs[(fn * 16 + lh) * LDP + kq * 8];
            #pragma unroll
            for (int fm = 0; fm < 2; ++fm)
                #pragma unroll
                for (int fn = 0; fn < 8; ++fn)
                    acc[fm][fn] = __builtin_amdgcn_mfma_f32_16x16x32_bf16(
                        af[fm], bfr[fn], acc[fm][fn], 0, 0, 0);
        }
    }

    // ---- epilogue: row = m0 + wave*32 + fm*16 + kq*4 + j, col = fn*16 + lh
    #pragma unroll
    for (int fm = 0; fm < 2; ++fm) {
        #pragma unroll
        for (int j = 0; j < 4; ++j) {
            int m = m0 + wave * 32 + fm * 16 + kq * 4 + j;
            if (m >= M) continue;
            float* Crow = &C[(size_t)m * CH];
            #pragma unroll
            for (int fn = 0; fn < 8; ++fn) {
                int col = fn * 16 + lh;
                float v = acc[fm][fn][j];
                if (bias) v += bias[col];
                if (accum) v += Crow[col];
                Crow[col] = v;
            }
        }
    }
}

// ---------------------------------------------------------------- BN -------

__global__ __launch_bounds__(256) void bnstats_k(const float* __restrict__ h,
                                                 float* __restrict__ sums, int M) {
    __shared__ float ls[512];
    int c = threadIdx.x & 127, half = threadIdx.x >> 7;
    float s = 0.f, q = 0.f;
    for (int r = blockIdx.x * 2 + half; r < M; r += gridDim.x * 2) {
        float v = h[(size_t)r * CH + c];
        s += v; q = fmaf(v, v, q);
    }
    ls[threadIdx.x] = s;
    ls[256 + threadIdx.x] = q;
    __syncthreads();
    if (half == 0) {
        atomicAdd(&sums[c],       s + ls[128 + c]);
        atomicAdd(&sums[128 + c], q + ls[256 + 128 + c]);
    }
}

__global__ void bncoef_k(const float* __restrict__ sums, const float* __restrict__ gamma,
                         const float* __restrict__ beta, float* __restrict__ coef,
                         float invM) {
    int c = threadIdx.x;  // 128 threads
    float m   = sums[c] * invM;
    float var = fmaxf(sums[128 + c] * invM - m * m, 0.f);
    float sc  = gamma[c] * rsqrtf(var + 1e-5f);
    coef[c]       = sc;
    coef[128 + c] = beta[c] - m * sc;
}

// apply BN + ReLU, fp32 in -> bf16 out (2 channels per thread)
__global__ __launch_bounds__(256) void bnapply_k(const float* __restrict__ h,
                                                 const float* __restrict__ coef,
                                                 unsigned int* __restrict__ outb, int M) {
    int total = M * 64;
    for (int idx = blockIdx.x * blockDim.x + threadIdx.x; idx < total;
         idx += gridDim.x * blockDim.x) {
        int c2 = (idx & 63) * 2;
        float2 v = ((const float2*)h)[idx];
        float a = fmaxf(fmaf(v.x, coef[c2 + 0], coef[128 + c2 + 0]), 0.f);
        float b = fmaxf(fmaf(v.y, coef[c2 + 1], coef[128 + c2 + 1]), 0.f);
        outb[idx] = (unsigned int)f2bf(a) | ((unsigned int)f2bf(b) << 16);
    }
}

// ---------------------------------------------------------------- launch ---

extern "C" void kernel_launch(void* const* d_in, const int* in_sizes, int n_in,
                              void* d_out, int out_size, void* d_ws, size_t ws_size,
                              hipStream_t stream) {
    const float* x      = (const float*)d_in[0];
    const int*   ei     = (const int*)d_in[1];
    const float* w1     = (const float*)d_in[2];
    const float* b1     = (const float*)d_in[3];
    const float* w2     = (const float*)d_in[4];
    const float* b2     = (const float*)d_in[5];
    const float* w3     = (const float*)d_in[6];
    const float* b3     = (const float*)d_in[7];
    const float* gamma1 = (const float*)d_in[8];
    const float* beta1  = (const float*)d_in[9];
    const float* gamma2 = (const float*)d_in[10];
    const float* beta2  = (const float*)d_in[11];
    float* out = (float*)d_out;

    const int M = in_sizes[0] / CH;   // 50000 nodes
    const int E = in_sizes[1] / 2;    // 600000 edges
    const int* srcp = ei;
    const int* dstp = ei + E;

    size_t off = 0;
    auto alloc = [&](size_t bytes) {
        void* p = (char*)d_ws + off;
        off += (bytes + 255) & ~(size_t)255;
        return p;
    };
    unsigned int* PB0 = (unsigned int*)alloc((size_t)M * CH * 2);  // bf16 feat
    unsigned int* PB1 = (unsigned int*)alloc((size_t)M * CH * 2);
    unsigned int* PB2 = (unsigned int*)alloc((size_t)M * CH * 2);
    unsigned int* PB3 = (unsigned int*)alloc((size_t)M * CH * 2);
    float* H      = (float*)alloc((size_t)M * CH * 4);             // fp32 pre-BN
    int2*  csw    = (int2*) alloc((size_t)E * 8);
    int*   degi   = (int*)  alloc((size_t)M * 4);
    int*   rowptr = (int*)  alloc((size_t)(M + 1) * 4);
    int*   fil    = (int*)  alloc((size_t)M * 4);
    float* dis    = (float*)alloc((size_t)M * 4);
    int*   bsum   = (int*)  alloc(4096);
    int*   bofs   = (int*)  alloc(4096);
    float* bnsums = (float*)alloc(1024);
    float* coef   = (float*)alloc(1024);
    short* Wt1    = (short*)alloc((size_t)1 * CH * CH * 2);
    short* Wt2    = (short*)alloc((size_t)3 * CH * CH * 2);
    short* Wt3    = (short*)alloc((size_t)5 * CH * CH * 2);
    (void)ws_size; (void)n_in; (void)out_size;

    const int nb = (M + 1023) / 1024;
    const int gb = (M + GEMM_BM - 1) / GEMM_BM;
    const int pgrid = (M + 3) / 4;

    // ---- graph setup: degree -> rowptr -> CSR ; weight conversion
    hipMemsetAsync(degi, 0, (size_t)M * 4, stream);
    hipMemsetAsync(fil,  0, (size_t)M * 4, stream);
    hist_k<<<(E + 255) / 256, 256, 0, stream>>>(dstp, degi, E);
    scan_partial_k<<<nb, 1024, 0, stream>>>(degi, rowptr, bsum, M);
    scan_bsums_k<<<1, 64, 0, stream>>>(bsum, bofs, nb, rowptr, M);
    scan_add_k<<<nb, 1024, 0, stream>>>(rowptr, bofs, M);
    dis_k<<<(M + 255) / 256, 256, 0, stream>>>(degi, dis, M);
    fill_k<<<(E + 255) / 256, 256, 0, stream>>>(srcp, dstp, rowptr, fil, dis, csw, E);
    wconv_k<<<(1 * 16384 + 255) / 256, 256, 0, stream>>>(w1, Wt1, 1 * 16384);
    wconv_k<<<(3 * 16384 + 255) / 256, 256, 0, stream>>>(w2, Wt2, 3 * 16384);
    wconv_k<<<(5 * 16384 + 255) / 256, 256, 0, stream>>>(w3, Wt3, 5 * 16384);

    // ---- layer 1: H = x @ W1 + b1 ; BN+ReLU -> PB0 (bf16)
    gemm_k<false><<<gb, 256, 0, stream>>>(x, nullptr, nullptr, Wt1, b1, H, M, 1, 0);
    hipMemsetAsync(bnsums, 0, 1024, stream);
    bnstats_k<<<256, 256, 0, stream>>>(H, bnsums, M);
    bncoef_k<<<1, 128, 0, stream>>>(bnsums, gamma1, beta1, coef, 1.f / (float)M);
    bnapply_k<<<2048, 256, 0, stream>>>(H, coef, PB0, M);

    // ---- layer 2 (K=3): Tx0=PB0, Tx1=PB1, Tx2=PB2 ; H = sum ; BN+ReLU -> PB0
    prop_k<<<pgrid, 256, 0, stream>>>(PB0, rowptr, csw, PB0, 1.f, 0.f, PB1, M);
    prop_k<<<pgrid, 256, 0, stream>>>(PB1, rowptr, csw, PB0, 2.f, -1.f, PB2, M);
    gemm_k<true><<<gb, 256, 0, stream>>>(PB0, PB1, PB2, Wt2, b2, H, M, 3, 0);
    hipMemsetAsync(bnsums, 0, 1024, stream);
    bnstats_k<<<256, 256, 0, stream>>>(H, bnsums, M);
    bncoef_k<<<1, 128, 0, stream>>>(bnsums, gamma2, beta2, coef, 1.f / (float)M);
    bnapply_k<<<2048, 256, 0, stream>>>(H, coef, PB0, M);

    // ---- layer 3 (K=5): Tx0=PB0
    prop_k<<<pgrid, 256, 0, stream>>>(PB0, rowptr, csw, PB0, 1.f, 0.f, PB1, M);
    prop_k<<<pgrid, 256, 0, stream>>>(PB1, rowptr, csw, PB0, 2.f, -1.f, PB2, M);
    gemm_k<true><<<gb, 256, 0, stream>>>(PB0, PB1, PB2, Wt3, b3, out, M, 3, 0); // k=0..2
    prop_k<<<pgrid, 256, 0, stream>>>(PB2, rowptr, csw, PB1, 2.f, -1.f, PB3, M); // Tx3
    prop_k<<<pgrid, 256, 0, stream>>>(PB3, rowptr, csw, PB2, 2.f, -1.f, PB0, M); // Tx4
    gemm_k<true><<<gb, 256, 0, stream>>>(PB3, PB0, nullptr, Wt3 + (size_t)3 * CH * CH,
                                         nullptr, out, M, 2, 1);                // k=3..4 accum
}

// Round 5
// 346.606 us; speedup vs baseline: 2.0670x; 1.3225x over previous
//
#include <hip/hip_runtime.h>

#define CH 128           // feature channels (CIN == COUT == 128)
#define GEMM_BM 128      // rows per GEMM block
#define KSTEP 32         // K chunk per MFMA stage
#define LDP 40           // LDS row pitch in bf16 elems (80B -> conflict-free-ish)

typedef __attribute__((ext_vector_type(8))) short bf16x8;
typedef __attribute__((ext_vector_type(4))) float f32x4;

static __device__ __forceinline__ unsigned short f2bf(float f) {
    unsigned int u = __float_as_uint(f);
    unsigned int r = (u + 0x7FFFu + ((u >> 16) & 1u)) >> 16;
    return (unsigned short)r;
}
static __device__ __forceinline__ float bflo(unsigned int v) {
    return __uint_as_float(v << 16);
}
static __device__ __forceinline__ float bfhi(unsigned int v) {
    return __uint_as_float(v & 0xffff0000u);
}

// ---------------------------------------------------------------- setup ----

__global__ void hist_k(const int* __restrict__ dst, int* __restrict__ deg, int E) {
    int e = blockIdx.x * blockDim.x + threadIdx.x;
    if (e < E) atomicAdd(&deg[dst[e]], 1);
}

__global__ __launch_bounds__(1024) void scan_partial_k(const int* __restrict__ deg,
                                                       int* __restrict__ rowptr,
                                                       int* __restrict__ bsum, int N) {
    __shared__ int sm[1024];
    int t = threadIdx.x;
    int i = blockIdx.x * 1024 + t;
    int v = (i < N) ? deg[i] : 0;
    sm[t] = v;
    __syncthreads();
    int x = v;
    for (int off = 1; off < 1024; off <<= 1) {
        int y = (t >= off) ? sm[t - off] : 0;
        __syncthreads();
        x += y;
        sm[t] = x;
        __syncthreads();
    }
    if (i < N) rowptr[i] = x - v;          // block-local exclusive
    if (t == 1023) bsum[blockIdx.x] = x;   // block total
}

__global__ void scan_bsums_k(const int* __restrict__ bsum, int* __restrict__ bofs,
                             int nb, int* __restrict__ rowptr, int N) {
    if (threadIdx.x == 0 && blockIdx.x == 0) {
        int run = 0;
        for (int b = 0; b < nb; ++b) { bofs[b] = run; run += bsum[b]; }
        rowptr[N] = run;   // == E
    }
}

__global__ __launch_bounds__(1024) void scan_add_k(int* __restrict__ rowptr,
                                                   const int* __restrict__ bofs, int N) {
    int i = blockIdx.x * 1024 + threadIdx.x;
    if (i < N) rowptr[i] += bofs[blockIdx.x];
}

__global__ void dis_k(const int* __restrict__ deg, float* __restrict__ dis, int N) {
    int n = blockIdx.x * blockDim.x + threadIdx.x;
    if (n < N) {
        int d = deg[n];
        dis[n] = (d > 0) ? rsqrtf((float)d) : 0.f;
    }
}

// CSR fill: one packed 8B scatter per edge
__global__ void fill_k(const int* __restrict__ src, const int* __restrict__ dst,
                       const int* __restrict__ rowptr, int* __restrict__ fill,
                       const float* __restrict__ dis, int2* __restrict__ csw, int E) {
    int e = blockIdx.x * blockDim.x + threadIdx.x;
    if (e >= E) return;
    int s = src[e], d = dst[e];
    int pos = rowptr[d] + atomicAdd(&fill[d], 1);
    csw[pos] = make_int2(s, __float_as_int(-dis[s] * dis[d]));
}

// weight convert: fp32 [p][k][c] -> bf16 transposed [p][c][k]
__global__ void wconv_k(const float* __restrict__ W, short* __restrict__ Wt, int total) {
    int idx = blockIdx.x * blockDim.x + threadIdx.x;
    if (idx >= total) return;
    int p = idx >> 14;
    int k = (idx >> 7) & 127;
    int c = idx & 127;
    Wt[(p << 14) + (c << 7) + k] = (short)f2bf(W[idx]);
}

// ---------------------------------------------------------------- prop -----
// bf16 features: row = 128 bf16 = 16 uint4. 16 lanes per node, uint4/lane
// (16B = coalescing sweet spot). 4 nodes per wave -> 4 independent edge
// chains; 4-wide unroll -> up to 16 gathers in flight per wave.
// out[n] = bf16( alpha * sum_e w[e]*xin[src[e]] + beta * other[n] )

__global__ __launch_bounds__(256) void prop_k(const uint4* __restrict__ xin,
                                              const int* __restrict__ rowptr,
                                              const int2* __restrict__ csw,
                                              const uint4* __restrict__ other,
                                              float alpha, float beta,
                                              uint4* __restrict__ out, int M) {
    int g = (blockIdx.x * 256 + threadIdx.x) >> 4;   // node index
    if (g >= M) return;
    int lane = threadIdx.x & 15;                     // sub-row 16B chunk
    int e0 = rowptr[g], e1 = rowptr[g + 1];
    float a0[8], a1[8];
    #pragma unroll
    for (int c = 0; c < 8; ++c) { a0[c] = 0.f; a1[c] = 0.f; }

    int e = e0;
    for (; e + 4 <= e1; e += 4) {
        int2 p0 = csw[e], p1 = csw[e + 1], p2 = csw[e + 2], p3 = csw[e + 3];
        uint4 v0 = xin[(size_t)p0.x * 16 + lane];
        uint4 v1 = xin[(size_t)p1.x * 16 + lane];
        uint4 v2 = xin[(size_t)p2.x * 16 + lane];
        uint4 v3 = xin[(size_t)p3.x * 16 + lane];
        float w0 = __int_as_float(p0.y), w1 = __int_as_float(p1.y);
        float w2 = __int_as_float(p2.y), w3 = __int_as_float(p3.y);
        a0[0] = fmaf(w0, bflo(v0.x), a0[0]); a0[1] = fmaf(w0, bfhi(v0.x), a0[1]);
        a0[2] = fmaf(w0, bflo(v0.y), a0[2]); a0[3] = fmaf(w0, bfhi(v0.y), a0[3]);
        a0[4] = fmaf(w0, bflo(v0.z), a0[4]); a0[5] = fmaf(w0, bfhi(v0.z), a0[5]);
        a0[6] = fmaf(w0, bflo(v0.w), a0[6]); a0[7] = fmaf(w0, bfhi(v0.w), a0[7]);
        a1[0] = fmaf(w1, bflo(v1.x), a1[0]); a1[1] = fmaf(w1, bfhi(v1.x), a1[1]);
        a1[2] = fmaf(w1, bflo(v1.y), a1[2]); a1[3] = fmaf(w1, bfhi(v1.y), a1[3]);
        a1[4] = fmaf(w1, bflo(v1.z), a1[4]); a1[5] = fmaf(w1, bfhi(v1.z), a1[5]);
        a1[6] = fmaf(w1, bflo(v1.w), a1[6]); a1[7] = fmaf(w1, bfhi(v1.w), a1[7]);
        a0[0] = fmaf(w2, bflo(v2.x), a0[0]); a0[1] = fmaf(w2, bfhi(v2.x), a0[1]);
        a0[2] = fmaf(w2, bflo(v2.y), a0[2]); a0[3] = fmaf(w2, bfhi(v2.y), a0[3]);
        a0[4] = fmaf(w2, bflo(v2.z), a0[4]); a0[5] = fmaf(w2, bfhi(v2.z), a0[5]);
        a0[6] = fmaf(w2, bflo(v2.w), a0[6]); a0[7] = fmaf(w2, bfhi(v2.w), a0[7]);
        a1[0] = fmaf(w3, bflo(v3.x), a1[0]); a1[1] = fmaf(w3, bfhi(v3.x), a1[1]);
        a1[2] = fmaf(w3, bflo(v3.y), a1[2]); a1[3] = fmaf(w3, bfhi(v3.y), a1[3]);
        a1[4] = fmaf(w3, bflo(v3.z), a1[4]); a1[5] = fmaf(w3, bfhi(v3.z), a1[5]);
        a1[6] = fmaf(w3, bflo(v3.w), a1[6]); a1[7] = fmaf(w3, bfhi(v3.w), a1[7]);
    }
    for (; e < e1; ++e) {
        int2 p0 = csw[e];
        uint4 v0 = xin[(size_t)p0.x * 16 + lane];
        float w0 = __int_as_float(p0.y);
        a0[0] = fmaf(w0, bflo(v0.x), a0[0]); a0[1] = fmaf(w0, bfhi(v0.x), a0[1]);
        a0[2] = fmaf(w0, bflo(v0.y), a0[2]); a0[3] = fmaf(w0, bfhi(v0.y), a0[3]);
        a0[4] = fmaf(w0, bflo(v0.z), a0[4]); a0[5] = fmaf(w0, bfhi(v0.z), a0[5]);
        a0[6] = fmaf(w0, bflo(v0.w), a0[6]); a0[7] = fmaf(w0, bfhi(v0.w), a0[7]);
    }

    float r[8];
    #pragma unroll
    for (int c = 0; c < 8; ++c) r[c] = alpha * (a0[c] + a1[c]);
    if (beta != 0.f) {
        uint4 o = other[(size_t)g * 16 + lane];
        r[0] = fmaf(beta, bflo(o.x), r[0]); r[1] = fmaf(beta, bfhi(o.x), r[1]);
        r[2] = fmaf(beta, bflo(o.y), r[2]); r[3] = fmaf(beta, bfhi(o.y), r[3]);
        r[4] = fmaf(beta, bflo(o.z), r[4]); r[5] = fmaf(beta, bfhi(o.z), r[5]);
        r[6] = fmaf(beta, bflo(o.w), r[6]); r[7] = fmaf(beta, bfhi(o.w), r[7]);
    }
    uint4 ov;
    ov.x = (unsigned int)f2bf(r[0]) | ((unsigned int)f2bf(r[1]) << 16);
    ov.y = (unsigned int)f2bf(r[2]) | ((unsigned int)f2bf(r[3]) << 16);
    ov.z = (unsigned int)f2bf(r[4]) | ((unsigned int)f2bf(r[5]) << 16);
    ov.w = (unsigned int)f2bf(r[6]) | ((unsigned int)f2bf(r[7]) << 16);
    out[(size_t)g * 16 + lane] = ov;
}

// ---------------------------------------------------------------- GEMM -----
// MFMA bf16 GEMM: C[m0:m0+128][0:128] (+)= sum_p A_p @ W_p (+ bias)
// ABF:   A is bf16 (else fp32, converted during staging).
// STATS: accumulate per-column sum/sumsq of output into sums[0:128]/[128:256]
//        (fused BatchNorm statistics; removes the separate bnstats pass).

template<bool ABF, bool STATS>
__global__ __launch_bounds__(256) void gemm_k(const void* __restrict__ A0_,
                                              const void* __restrict__ A1_,
                                              const void* __restrict__ A2_,
                                              const short* __restrict__ Wt,
                                              const float* __restrict__ bias,
                                              float* __restrict__ C,
                                              float* __restrict__ sums,
                                              int M, int nP, int accum) {
    __shared__ short As[128 * LDP];   // [row][k] padded
    __shared__ short Bs[128 * LDP];   // [col][k] padded
    __shared__ float red[2][4][128];  // stats: [s|q][wave][col]
    int t = threadIdx.x;
    int m0 = blockIdx.x * GEMM_BM;
    int wave = t >> 6;
    int lane = t & 63;
    int lh = lane & 15;        // fragment row/col within 16
    int kq = lane >> 4;        // k-group 0..3

    f32x4 acc[2][8];
    #pragma unroll
    for (int i = 0; i < 2; ++i)
        #pragma unroll
        for (int j = 0; j < 8; ++j) acc[i][j] = (f32x4){0.f, 0.f, 0.f, 0.f};

    const void* Aps[3] = {A0_, A1_, A2_};
    int srow = t >> 1;                 // staging row/col 0..127
    int skh  = (t & 1) << 4;           // staging k offset 0 or 16

    for (int p = 0; p < nP; ++p) {
        const short* Wp = Wt + ((size_t)p << 14);
        for (int k0 = 0; k0 < CH; k0 += KSTEP) {
            __syncthreads();   // previous tile fully consumed
            // ---- stage A: 128 rows x 32 k
            if (ABF) {
                const unsigned short* A = (const unsigned short*)Aps[p];
                bf16x8 lo = {0,0,0,0,0,0,0,0}, hi = {0,0,0,0,0,0,0,0};
                if (m0 + srow < M) {
                    const bf16x8* src = (const bf16x8*)&A[(size_t)(m0 + srow) * CH + k0 + skh];
                    lo = src[0]; hi = src[1];
                }
                *(bf16x8*)&As[srow * LDP + skh]     = lo;
                *(bf16x8*)&As[srow * LDP + skh + 8] = hi;
            } else {
                const float* A = (const float*)Aps[p];
                float4 v0, v1, v2, v3;
                if (m0 + srow < M) {
                    const float4* src = (const float4*)&A[(size_t)(m0 + srow) * CH + k0 + skh];
                    v0 = src[0]; v1 = src[1]; v2 = src[2]; v3 = src[3];
                } else {
                    v0 = v1 = v2 = v3 = make_float4(0.f, 0.f, 0.f, 0.f);
                }
                bf16x8 lo, hi;
                lo[0] = (short)f2bf(v0.x); lo[1] = (short)f2bf(v0.y);
                lo[2] = (short)f2bf(v0.z); lo[3] = (short)f2bf(v0.w);
                lo[4] = (short)f2bf(v1.x); lo[5] = (short)f2bf(v1.y);
                lo[6] = (short)f2bf(v1.z); lo[7] = (short)f2bf(v1.w);
                hi[0] = (short)f2bf(v2.x); hi[1] = (short)f2bf(v2.y);
                hi[2] = (short)f2bf(v2.z); hi[3] = (short)f2bf(v2.w);
                hi[4] = (short)f2bf(v3.x); hi[5] = (short)f2bf(v3.y);
                hi[6] = (short)f2bf(v3.z); hi[7] = (short)f2bf(v3.w);
                *(bf16x8*)&As[srow * LDP + skh]     = lo;
                *(bf16x8*)&As[srow * LDP + skh + 8] = hi;
            }
            // ---- stage B: 128 cols x 32 k, already bf16 [col][k]
            {
                const bf16x8* src = (const bf16x8*)&Wp[(srow << 7) + k0 + skh];
                *(bf16x8*)&Bs[srow * LDP + skh]     = src[0];
                *(bf16x8*)&Bs[srow * LDP + skh + 8] = src[1];
            }
            __syncthreads();
            // ---- fragments + MFMA
            bf16x8 af[2], bfr[8];
            #pragma unroll
            for (int fm = 0; fm < 2; ++fm)
                af[fm] = *(const bf16x8*)&As[(wave * 32 + fm * 16 + lh) * LDP + kq * 8];
            #pragma unroll
            for (int fn = 0; fn < 8; ++fn)
                bfr[fn] = *(const bf16x8*)&Bs[(fn * 16 + lh) * LDP + kq * 8];
            #pragma unroll
            for (int fm = 0; fm < 2; ++fm)
                #pragma unroll
                for (int fn = 0; fn < 8; ++fn)
                    acc[fm][fn] = __builtin_amdgcn_mfma_f32_16x16x32_bf16(
                        af[fm], bfr[fn], acc[fm][fn], 0, 0, 0);
        }
    }

    // ---- epilogue: row = m0 + wave*32 + fm*16 + kq*4 + j, col = fn*16 + lh
    float s[8], q[8];
    #pragma unroll
    for (int fn = 0; fn < 8; ++fn) { s[fn] = 0.f; q[fn] = 0.f; }
    float bj[8];
    #pragma unroll
    for (int fn = 0; fn < 8; ++fn) bj[fn] = bias ? bias[fn * 16 + lh] : 0.f;

    #pragma unroll
    for (int fm = 0; fm < 2; ++fm) {
        #pragma unroll
        for (int j = 0; j < 4; ++j) {
            int m = m0 + wave * 32 + fm * 16 + kq * 4 + j;
            if (m >= M) continue;
            float* Crow = &C[(size_t)m * CH];
            #pragma unroll
            for (int fn = 0; fn < 8; ++fn) {
                int col = fn * 16 + lh;
                float v = acc[fm][fn][j] + bj[fn];
                if (accum) v += Crow[col];
                if (STATS) { s[fn] += v; q[fn] = fmaf(v, v, q[fn]); }
                Crow[col] = v;
            }
        }
    }

    if (STATS) {
        // reduce across kq groups (lanes 16/32 apart share the same col)
        #pragma unroll
        for (int fn = 0; fn < 8; ++fn) {
            s[fn] += __shfl_xor(s[fn], 16); s[fn] += __shfl_xor(s[fn], 32);
            q[fn] += __shfl_xor(q[fn], 16); q[fn] += __shfl_xor(q[fn], 32);
        }
        if (kq == 0) {
            #pragma unroll
            for (int fn = 0; fn < 8; ++fn) {
                red[0][wave][fn * 16 + lh] = s[fn];
                red[1][wave][fn * 16 + lh] = q[fn];
            }
        }
        __syncthreads();
        if (t < 128) {
            float ss = red[0][0][t] + red[0][1][t] + red[0][2][t] + red[0][3][t];
            float qq = red[1][0][t] + red[1][1][t] + red[1][2][t] + red[1][3][t];
            atomicAdd(&sums[t], ss);
            atomicAdd(&sums[128 + t], qq);
        }
    }
}

// ---------------------------------------------------------------- BN -------

__global__ void bncoef_k(const float* __restrict__ sums, const float* __restrict__ gamma,
                         const float* __restrict__ beta, float* __restrict__ coef,
                         float invM) {
    int c = threadIdx.x;  // 128 threads
    float m   = sums[c] * invM;
    float var = fmaxf(sums[128 + c] * invM - m * m, 0.f);
    float sc  = gamma[c] * rsqrtf(var + 1e-5f);
    coef[c]       = sc;
    coef[128 + c] = beta[c] - m * sc;
}

// apply BN + ReLU, fp32 in -> bf16 out (2 channels per thread)
__global__ __launch_bounds__(256) void bnapply_k(const float* __restrict__ h,
                                                 const float* __restrict__ coef,
                                                 unsigned int* __restrict__ outb, int M) {
    int total = M * 64;
    for (int idx = blockIdx.x * blockDim.x + threadIdx.x; idx < total;
         idx += gridDim.x * blockDim.x) {
        int c2 = (idx & 63) * 2;
        float2 v = ((const float2*)h)[idx];
        float a = fmaxf(fmaf(v.x, coef[c2 + 0], coef[128 + c2 + 0]), 0.f);
        float b = fmaxf(fmaf(v.y, coef[c2 + 1], coef[128 + c2 + 1]), 0.f);
        outb[idx] = (unsigned int)f2bf(a) | ((unsigned int)f2bf(b) << 16);
    }
}

// ---------------------------------------------------------------- launch ---

extern "C" void kernel_launch(void* const* d_in, const int* in_sizes, int n_in,
                              void* d_out, int out_size, void* d_ws, size_t ws_size,
                              hipStream_t stream) {
    const float* x      = (const float*)d_in[0];
    const int*   ei     = (const int*)d_in[1];
    const float* w1     = (const float*)d_in[2];
    const float* b1     = (const float*)d_in[3];
    const float* w2     = (const float*)d_in[4];
    const float* b2     = (const float*)d_in[5];
    const float* w3     = (const float*)d_in[6];
    const float* b3     = (const float*)d_in[7];
    const float* gamma1 = (const float*)d_in[8];
    const float* beta1  = (const float*)d_in[9];
    const float* gamma2 = (const float*)d_in[10];
    const float* beta2  = (const float*)d_in[11];
    float* out = (float*)d_out;

    const int M = in_sizes[0] / CH;   // 50000 nodes
    const int E = in_sizes[1] / 2;    // 600000 edges
    const int* srcp = ei;
    const int* dstp = ei + E;

    size_t off = 0;
    auto alloc = [&](size_t bytes) {
        void* p = (char*)d_ws + off;
        off += (bytes + 255) & ~(size_t)255;
        return p;
    };
    unsigned int* PB0 = (unsigned int*)alloc((size_t)M * CH * 2);  // bf16 feat
    unsigned int* PB1 = (unsigned int*)alloc((size_t)M * CH * 2);
    unsigned int* PB2 = (unsigned int*)alloc((size_t)M * CH * 2);
    unsigned int* PB3 = (unsigned int*)alloc((size_t)M * CH * 2);
    float* H      = (float*)alloc((size_t)M * CH * 4);             // fp32 pre-BN
    int2*  csw    = (int2*) alloc((size_t)E * 8);
    int*   degi   = (int*)  alloc((size_t)M * 4);
    int*   rowptr = (int*)  alloc((size_t)(M + 1) * 4);
    int*   fil    = (int*)  alloc((size_t)M * 4);
    float* dis    = (float*)alloc((size_t)M * 4);
    int*   bsum   = (int*)  alloc(4096);
    int*   bofs   = (int*)  alloc(4096);
    float* bnsums = (float*)alloc(1024);
    float* coef   = (float*)alloc(1024);
    short* Wt1    = (short*)alloc((size_t)1 * CH * CH * 2);
    short* Wt2    = (short*)alloc((size_t)3 * CH * CH * 2);
    short* Wt3    = (short*)alloc((size_t)5 * CH * CH * 2);
    (void)ws_size; (void)n_in; (void)out_size;

    const int nb = (M + 1023) / 1024;
    const int gb = (M + GEMM_BM - 1) / GEMM_BM;
    const int pgrid = (M + 15) / 16;   // 16 nodes per 256-thread block

    // ---- graph setup: degree -> rowptr -> CSR ; weight conversion
    hipMemsetAsync(degi, 0, (size_t)M * 4, stream);
    hipMemsetAsync(fil,  0, (size_t)M * 4, stream);
    hist_k<<<(E + 255) / 256, 256, 0, stream>>>(dstp, degi, E);
    scan_partial_k<<<nb, 1024, 0, stream>>>(degi, rowptr, bsum, M);
    scan_bsums_k<<<1, 64, 0, stream>>>(bsum, bofs, nb, rowptr, M);
    scan_add_k<<<nb, 1024, 0, stream>>>(rowptr, bofs, M);
    dis_k<<<(M + 255) / 256, 256, 0, stream>>>(degi, dis, M);
    fill_k<<<(E + 255) / 256, 256, 0, stream>>>(srcp, dstp, rowptr, fil, dis, csw, E);
    wconv_k<<<(1 * 16384 + 255) / 256, 256, 0, stream>>>(w1, Wt1, 1 * 16384);
    wconv_k<<<(3 * 16384 + 255) / 256, 256, 0, stream>>>(w2, Wt2, 3 * 16384);
    wconv_k<<<(5 * 16384 + 255) / 256, 256, 0, stream>>>(w3, Wt3, 5 * 16384);

    // ---- layer 1: H = x @ W1 + b1 (stats fused) ; BN+ReLU -> PB0 (bf16)
    hipMemsetAsync(bnsums, 0, 1024, stream);
    gemm_k<false, true><<<gb, 256, 0, stream>>>(x, nullptr, nullptr, Wt1, b1, H,
                                                bnsums, M, 1, 0);
    bncoef_k<<<1, 128, 0, stream>>>(bnsums, gamma1, beta1, coef, 1.f / (float)M);
    bnapply_k<<<2048, 256, 0, stream>>>(H, coef, PB0, M);

    // ---- layer 2 (K=3): Tx0=PB0, Tx1=PB1, Tx2=PB2 ; H = sum ; BN+ReLU -> PB0
    prop_k<<<pgrid, 256, 0, stream>>>((const uint4*)PB0, rowptr, csw,
                                      (const uint4*)PB0, 1.f, 0.f, (uint4*)PB1, M);
    prop_k<<<pgrid, 256, 0, stream>>>((const uint4*)PB1, rowptr, csw,
                                      (const uint4*)PB0, 2.f, -1.f, (uint4*)PB2, M);
    hipMemsetAsync(bnsums, 0, 1024, stream);
    gemm_k<true, true><<<gb, 256, 0, stream>>>(PB0, PB1, PB2, Wt2, b2, H,
                                               bnsums, M, 3, 0);
    bncoef_k<<<1, 128, 0, stream>>>(bnsums, gamma2, beta2, coef, 1.f / (float)M);
    bnapply_k<<<2048, 256, 0, stream>>>(H, coef, PB0, M);

    // ---- layer 3 (K=5): Tx0=PB0
    prop_k<<<pgrid, 256, 0, stream>>>((const uint4*)PB0, rowptr, csw,
                                      (const uint4*)PB0, 1.f, 0.f, (uint4*)PB1, M);
    prop_k<<<pgrid, 256, 0, stream>>>((const uint4*)PB1, rowptr, csw,
                                      (const uint4*)PB0, 2.f, -1.f, (uint4*)PB2, M);
    gemm_k<true, false><<<gb, 256, 0, stream>>>(PB0, PB1, PB2, Wt3, b3, out,
                                                nullptr, M, 3, 0);            // k=0..2
    prop_k<<<pgrid, 256, 0, stream>>>((const uint4*)PB2, rowptr, csw,
                                      (const uint4*)PB1, 2.f, -1.f, (uint4*)PB3, M); // Tx3
    prop_k<<<pgrid, 256, 0, stream>>>((const uint4*)PB3, rowptr, csw,
                                      (const uint4*)PB2, 2.f, -1.f, (uint4*)PB0, M); // Tx4
    gemm_k<true, false><<<gb, 256, 0, stream>>>(PB3, PB0, nullptr,
                                                Wt3 + (size_t)3 * CH * CH,
                                                nullptr, out, nullptr, M, 2, 1); // k=3..4 accum
}

// Round 6
// 303.769 us; speedup vs baseline: 2.3585x; 1.1410x over previous
//
#include <hip/hip_runtime.h>

#define CH 128           // feature channels (CIN == COUT == 128)
#define GEMM_BM 128      // rows per GEMM block
#define KSTEP 32         // K chunk per MFMA stage
#define LDP 40           // LDS row pitch in bf16 elems (80B -> 2-way max on b128 reads)

typedef __attribute__((ext_vector_type(8))) short bf16x8;
typedef __attribute__((ext_vector_type(4))) float f32x4;

static __device__ __forceinline__ unsigned short f2bf(float f) {
    unsigned int u = __float_as_uint(f);
    unsigned int r = (u + 0x7FFFu + ((u >> 16) & 1u)) >> 16;
    return (unsigned short)r;
}
static __device__ __forceinline__ float bflo(unsigned int v) {
    return __uint_as_float(v << 16);
}
static __device__ __forceinline__ float bfhi(unsigned int v) {
    return __uint_as_float(v & 0xffff0000u);
}

// ---------------------------------------------------------------- setup ----

__global__ void hist_k(const int* __restrict__ dst, int* __restrict__ deg, int E) {
    int e = blockIdx.x * blockDim.x + threadIdx.x;
    if (e < E) atomicAdd(&deg[dst[e]], 1);
}

__global__ __launch_bounds__(1024) void scan_partial_k(const int* __restrict__ deg,
                                                       int* __restrict__ rowptr,
                                                       int* __restrict__ bsum, int N) {
    __shared__ int sm[1024];
    int t = threadIdx.x;
    int i = blockIdx.x * 1024 + t;
    int v = (i < N) ? deg[i] : 0;
    sm[t] = v;
    __syncthreads();
    int x = v;
    for (int off = 1; off < 1024; off <<= 1) {
        int y = (t >= off) ? sm[t - off] : 0;
        __syncthreads();
        x += y;
        sm[t] = x;
        __syncthreads();
    }
    if (i < N) rowptr[i] = x - v;          // block-local exclusive
    if (t == 1023) bsum[blockIdx.x] = x;   // block total
}

// adds block offsets (prefix of bsum computed in-block); last block writes rowptr[N]
__global__ __launch_bounds__(1024) void scan_add2_k(int* __restrict__ rowptr,
                                                    const int* __restrict__ bsum,
                                                    int nb, int N) {
    __shared__ int soff;
    if (threadIdx.x == 0) {
        int run = 0;
        for (int b = 0; b < (int)blockIdx.x; ++b) run += bsum[b];
        soff = run;
        if ((int)blockIdx.x == nb - 1) {
            int tot = run;
            for (int b = blockIdx.x; b < nb; ++b) tot += bsum[b];
            rowptr[N] = tot;   // == E
        }
    }
    __syncthreads();
    int i = blockIdx.x * 1024 + threadIdx.x;
    if (i < N) rowptr[i] += soff;
}

// CSR fill: one packed 8B scatter per edge; deg^{-1/2} computed inline
__global__ void fill_k(const int* __restrict__ src, const int* __restrict__ dst,
                       const int* __restrict__ rowptr, int* __restrict__ fill,
                       const int* __restrict__ deg, int2* __restrict__ csw, int E) {
    int e = blockIdx.x * blockDim.x + threadIdx.x;
    if (e >= E) return;
    int s = src[e], d = dst[e];
    int ds_ = deg[s], dd = deg[d];
    float dis = (ds_ > 0) ? rsqrtf((float)ds_) : 0.f;
    float did = (dd  > 0) ? rsqrtf((float)dd)  : 0.f;
    int pos = rowptr[d] + atomicAdd(&fill[d], 1);
    csw[pos] = make_int2(s, __float_as_int(-dis * did));
}

// weight convert: all 9 pieces (w1|w2|w3) fp32 [p][k][c] -> bf16 transposed [p][c][k]
__global__ void wconv_k(const float* __restrict__ w1, const float* __restrict__ w2,
                        const float* __restrict__ w3, short* __restrict__ Wt, int total) {
    int idx = blockIdx.x * blockDim.x + threadIdx.x;
    if (idx >= total) return;
    int p = idx >> 14;
    int k = (idx >> 7) & 127;
    int c = idx & 127;
    float v;
    if (p == 0)      v = w1[idx];
    else if (p <= 3) v = w2[idx - (1 << 14)];
    else             v = w3[idx - (4 << 14)];
    Wt[(p << 14) + (c << 7) + k] = (short)f2bf(v);
}

// ---------------------------------------------------------------- prop -----
// bf16 features: row = 128 bf16 = 16 uint4. 16 lanes per node, uint4/lane.
// out[n] = bf16( alpha * sum_e w[e]*xin[src[e]] + beta * other[n] )

__global__ __launch_bounds__(256) void prop_k(const uint4* __restrict__ xin,
                                              const int* __restrict__ rowptr,
                                              const int2* __restrict__ csw,
                                              const uint4* __restrict__ other,
                                              float alpha, float beta,
                                              uint4* __restrict__ out, int M) {
    int g = (blockIdx.x * 256 + threadIdx.x) >> 4;   // node index
    if (g >= M) return;
    int lane = threadIdx.x & 15;                     // sub-row 16B chunk
    int e0 = rowptr[g], e1 = rowptr[g + 1];
    float a0[8], a1[8];
    #pragma unroll
    for (int c = 0; c < 8; ++c) { a0[c] = 0.f; a1[c] = 0.f; }

    int e = e0;
    for (; e + 4 <= e1; e += 4) {
        int2 p0 = csw[e], p1 = csw[e + 1], p2 = csw[e + 2], p3 = csw[e + 3];
        uint4 v0 = xin[(size_t)p0.x * 16 + lane];
        uint4 v1 = xin[(size_t)p1.x * 16 + lane];
        uint4 v2 = xin[(size_t)p2.x * 16 + lane];
        uint4 v3 = xin[(size_t)p3.x * 16 + lane];
        float w0 = __int_as_float(p0.y), w1 = __int_as_float(p1.y);
        float w2 = __int_as_float(p2.y), w3 = __int_as_float(p3.y);
        a0[0] = fmaf(w0, bflo(v0.x), a0[0]); a0[1] = fmaf(w0, bfhi(v0.x), a0[1]);
        a0[2] = fmaf(w0, bflo(v0.y), a0[2]); a0[3] = fmaf(w0, bfhi(v0.y), a0[3]);
        a0[4] = fmaf(w0, bflo(v0.z), a0[4]); a0[5] = fmaf(w0, bfhi(v0.z), a0[5]);
        a0[6] = fmaf(w0, bflo(v0.w), a0[6]); a0[7] = fmaf(w0, bfhi(v0.w), a0[7]);
        a1[0] = fmaf(w1, bflo(v1.x), a1[0]); a1[1] = fmaf(w1, bfhi(v1.x), a1[1]);
        a1[2] = fmaf(w1, bflo(v1.y), a1[2]); a1[3] = fmaf(w1, bfhi(v1.y), a1[3]);
        a1[4] = fmaf(w1, bflo(v1.z), a1[4]); a1[5] = fmaf(w1, bfhi(v1.z), a1[5]);
        a1[6] = fmaf(w1, bflo(v1.w), a1[6]); a1[7] = fmaf(w1, bfhi(v1.w), a1[7]);
        a0[0] = fmaf(w2, bflo(v2.x), a0[0]); a0[1] = fmaf(w2, bfhi(v2.x), a0[1]);
        a0[2] = fmaf(w2, bflo(v2.y), a0[2]); a0[3] = fmaf(w2, bfhi(v2.y), a0[3]);
        a0[4] = fmaf(w2, bflo(v2.z), a0[4]); a0[5] = fmaf(w2, bfhi(v2.z), a0[5]);
        a0[6] = fmaf(w2, bflo(v2.w), a0[6]); a0[7] = fmaf(w2, bfhi(v2.w), a0[7]);
        a1[0] = fmaf(w3, bflo(v3.x), a1[0]); a1[1] = fmaf(w3, bfhi(v3.x), a1[1]);
        a1[2] = fmaf(w3, bflo(v3.y), a1[2]); a1[3] = fmaf(w3, bfhi(v3.y), a1[3]);
        a1[4] = fmaf(w3, bflo(v3.z), a1[4]); a1[5] = fmaf(w3, bfhi(v3.z), a1[5]);
        a1[6] = fmaf(w3, bflo(v3.w), a1[6]); a1[7] = fmaf(w3, bfhi(v3.w), a1[7]);
    }
    for (; e < e1; ++e) {
        int2 p0 = csw[e];
        uint4 v0 = xin[(size_t)p0.x * 16 + lane];
        float w0 = __int_as_float(p0.y);
        a0[0] = fmaf(w0, bflo(v0.x), a0[0]); a0[1] = fmaf(w0, bfhi(v0.x), a0[1]);
        a0[2] = fmaf(w0, bflo(v0.y), a0[2]); a0[3] = fmaf(w0, bfhi(v0.y), a0[3]);
        a0[4] = fmaf(w0, bflo(v0.z), a0[4]); a0[5] = fmaf(w0, bfhi(v0.z), a0[5]);
        a0[6] = fmaf(w0, bflo(v0.w), a0[6]); a0[7] = fmaf(w0, bfhi(v0.w), a0[7]);
    }

    float r[8];
    #pragma unroll
    for (int c = 0; c < 8; ++c) r[c] = alpha * (a0[c] + a1[c]);
    if (beta != 0.f) {
        uint4 o = other[(size_t)g * 16 + lane];
        r[0] = fmaf(beta, bflo(o.x), r[0]); r[1] = fmaf(beta, bfhi(o.x), r[1]);
        r[2] = fmaf(beta, bflo(o.y), r[2]); r[3] = fmaf(beta, bfhi(o.y), r[3]);
        r[4] = fmaf(beta, bflo(o.z), r[4]); r[5] = fmaf(beta, bfhi(o.z), r[5]);
        r[6] = fmaf(beta, bflo(o.w), r[6]); r[7] = fmaf(beta, bfhi(o.w), r[7]);
    }
    uint4 ov;
    ov.x = (unsigned int)f2bf(r[0]) | ((unsigned int)f2bf(r[1]) << 16);
    ov.y = (unsigned int)f2bf(r[2]) | ((unsigned int)f2bf(r[3]) << 16);
    ov.z = (unsigned int)f2bf(r[4]) | ((unsigned int)f2bf(r[5]) << 16);
    ov.w = (unsigned int)f2bf(r[6]) | ((unsigned int)f2bf(r[7]) << 16);
    out[(size_t)g * 16 + lane] = ov;
}

// ---------------------------------------------------------------- GEMM -----
// MFMA bf16 GEMM: C[m0:m0+128][0:128] = sum_{p<nP} A_p @ W_p (+ bias)
// Pipelined: B staged once per piece (4 K-tiles resident in LDS);
// A register-prefetched + LDS double-buffered (1 barrier per K-step).
// ABF:   A is bf16 (else fp32, converted during staging).
// STATS: fused per-column BatchNorm sum/sumsq into sums[0:256].

template<bool ABF, bool STATS>
__global__ __launch_bounds__(256) void gemm_k(const void* __restrict__ A0_,
                                              const void* __restrict__ A1_,
                                              const void* __restrict__ A2_,
                                              const void* __restrict__ A3_,
                                              const void* __restrict__ A4_,
                                              const short* __restrict__ Wt,
                                              const float* __restrict__ bias,
                                              float* __restrict__ C,
                                              float* __restrict__ sums,
                                              int M, int nP) {
    __shared__ short As[2][128 * LDP];   // A dbuf [row][k] padded
    __shared__ short Bs[4][128 * LDP];   // whole piece of B [k-tile][col][k]
    int t = threadIdx.x;
    int m0 = blockIdx.x * GEMM_BM;
    int wave = t >> 6;
    int lane = t & 63;
    int lh = lane & 15;        // fragment row/col within 16
    int kq = lane >> 4;        // k-group 0..3

    f32x4 acc[2][8];
    #pragma unroll
    for (int i = 0; i < 2; ++i)
        #pragma unroll
        for (int j = 0; j < 8; ++j) acc[i][j] = (f32x4){0.f, 0.f, 0.f, 0.f};

    const void* Aps[5] = {A0_, A1_, A2_, A3_, A4_};
    int srow = t >> 1;                 // staging row 0..127
    int skh  = (t & 1) << 4;           // staging k offset 0 or 16
    const bool rowok = (m0 + srow < M);
    int nsteps = nP * 4;

    // ---- prefetch A for step 0 into regs
    bf16x8 ra0 = {0,0,0,0,0,0,0,0}, ra1 = {0,0,0,0,0,0,0,0};
    float4 rf0, rf1, rf2, rf3;
    if (ABF) {
        if (rowok) {
            const bf16x8* src = (const bf16x8*)
                &((const unsigned short*)Aps[0])[(size_t)(m0 + srow) * CH + skh];
            ra0 = src[0]; ra1 = src[1];
        }
    } else {
        rf0 = rf1 = rf2 = rf3 = make_float4(0.f, 0.f, 0.f, 0.f);
        if (rowok) {
            const float4* src = (const float4*)
                &((const float*)Aps[0])[(size_t)(m0 + srow) * CH + skh];
            rf0 = src[0]; rf1 = src[1]; rf2 = src[2]; rf3 = src[3];
        }
    }

    for (int s = 0; s < nsteps; ++s) {
        int k = s & 3;
        if (k == 0) {
            if (s > 0) __syncthreads();   // prev piece's Bs reads complete
            const short* Wp = Wt + ((size_t)(s >> 2) << 14);
            #pragma unroll
            for (int kt = 0; kt < 4; ++kt) {
                const bf16x8* srcB = (const bf16x8*)&Wp[(srow << 7) + kt * KSTEP + skh];
                *(bf16x8*)&Bs[kt][srow * LDP + skh]     = srcB[0];
                *(bf16x8*)&Bs[kt][srow * LDP + skh + 8] = srcB[1];
            }
        }
        // ---- write prefetched A regs -> LDS (dbuf)
        if (ABF) {
            *(bf16x8*)&As[s & 1][srow * LDP + skh]     = ra0;
            *(bf16x8*)&As[s & 1][srow * LDP + skh + 8] = ra1;
        } else {
            bf16x8 lo, hi;
            lo[0] = (short)f2bf(rf0.x); lo[1] = (short)f2bf(rf0.y);
            lo[2] = (short)f2bf(rf0.z); lo[3] = (short)f2bf(rf0.w);
            lo[4] = (short)f2bf(rf1.x); lo[5] = (short)f2bf(rf1.y);
            lo[6] = (short)f2bf(rf1.z); lo[7] = (short)f2bf(rf1.w);
            hi[0] = (short)f2bf(rf2.x); hi[1] = (short)f2bf(rf2.y);
            hi[2] = (short)f2bf(rf2.z); hi[3] = (short)f2bf(rf2.w);
            hi[4] = (short)f2bf(rf3.x); hi[5] = (short)f2bf(rf3.y);
            hi[6] = (short)f2bf(rf3.z); hi[7] = (short)f2bf(rf3.w);
            *(bf16x8*)&As[s & 1][srow * LDP + skh]     = lo;
            *(bf16x8*)&As[s & 1][srow * LDP + skh + 8] = hi;
        }
        __syncthreads();
        // ---- prefetch A for step s+1 (overlaps with MFMAs below)
        if (s + 1 < nsteps) {
            int p1 = (s + 1) >> 2, k1 = ((s + 1) & 3) * KSTEP;
            if (ABF) {
                ra0 = (bf16x8){0,0,0,0,0,0,0,0}; ra1 = ra0;
                if (rowok) {
                    const bf16x8* src = (const bf16x8*)
                        &((const unsigned short*)Aps[p1])[(size_t)(m0 + srow) * CH + k1 + skh];
                    ra0 = src[0]; ra1 = src[1];
                }
            } else {
                rf0 = rf1 = rf2 = rf3 = make_float4(0.f, 0.f, 0.f, 0.f);
                if (rowok) {
                    const float4* src = (const float4*)
                        &((const float*)Aps[p1])[(size_t)(m0 + srow) * CH + k1 + skh];
                    rf0 = src[0]; rf1 = src[1]; rf2 = src[2]; rf3 = src[3];
                }
            }
        }
        // ---- fragments + MFMA
        bf16x8 af[2], bfr[8];
        #pragma unroll
        for (int fm = 0; fm < 2; ++fm)
            af[fm] = *(const bf16x8*)&As[s & 1][(wave * 32 + fm * 16 + lh) * LDP + kq * 8];
        #pragma unroll
        for (int fn = 0; fn < 8; ++fn)
            bfr[fn] = *(const bf16x8*)&Bs[k][(fn * 16 + lh) * LDP + kq * 8];
        #pragma unroll
        for (int fm = 0; fm < 2; ++fm)
            #pragma unroll
            for (int fn = 0; fn < 8; ++fn)
                acc[fm][fn] = __builtin_amdgcn_mfma_f32_16x16x32_bf16(
                    af[fm], bfr[fn], acc[fm][fn], 0, 0, 0);
    }

    // ---- epilogue: row = m0 + wave*32 + fm*16 + kq*4 + j, col = fn*16 + lh
    float s_[8], q_[8];
    #pragma unroll
    for (int fn = 0; fn < 8; ++fn) { s_[fn] = 0.f; q_[fn] = 0.f; }
    float bj[8];
    #pragma unroll
    for (int fn = 0; fn < 8; ++fn) bj[fn] = bias ? bias[fn * 16 + lh] : 0.f;

    #pragma unroll
    for (int fm = 0; fm < 2; ++fm) {
        #pragma unroll
        for (int j = 0; j < 4; ++j) {
            int m = m0 + wave * 32 + fm * 16 + kq * 4 + j;
            if (m >= M) continue;
            float* Crow = &C[(size_t)m * CH];
            #pragma unroll
            for (int fn = 0; fn < 8; ++fn) {
                int col = fn * 16 + lh;
                float v = acc[fm][fn][j] + bj[fn];
                if (STATS) { s_[fn] += v; q_[fn] = fmaf(v, v, q_[fn]); }
                Crow[col] = v;
            }
        }
    }

    if (STATS) {
        #pragma unroll
        for (int fn = 0; fn < 8; ++fn) {
            s_[fn] += __shfl_xor(s_[fn], 16); s_[fn] += __shfl_xor(s_[fn], 32);
            q_[fn] += __shfl_xor(q_[fn], 16); q_[fn] += __shfl_xor(q_[fn], 32);
        }
        float* red = (float*)&As[0][0];   // reuse As LDS: [2][4][128] floats
        __syncthreads();                  // all waves done reading As/Bs
        if (kq == 0) {
            #pragma unroll
            for (int fn = 0; fn < 8; ++fn) {
                red[(0 * 4 + wave) * 128 + fn * 16 + lh] = s_[fn];
                red[(1 * 4 + wave) * 128 + fn * 16 + lh] = q_[fn];
            }
        }
        __syncthreads();
        if (t < 128) {
            float ss = red[0 * 128 + t] + red[1 * 128 + t] + red[2 * 128 + t] + red[3 * 128 + t];
            float qq = red[4 * 128 + t] + red[5 * 128 + t] + red[6 * 128 + t] + red[7 * 128 + t];
            atomicAdd(&sums[t], ss);
            atomicAdd(&sums[128 + t], qq);
        }
    }
}

// ---------------------------------------------------------------- BN -------
// BN coef computed per block from fused stats; apply + ReLU, fp32 -> bf16

__global__ __launch_bounds__(256) void bnapply_k(const float* __restrict__ h,
                                                 const float* __restrict__ sums,
                                                 const float* __restrict__ gamma,
                                                 const float* __restrict__ beta,
                                                 float invM,
                                                 unsigned int* __restrict__ outb, int M) {
    __shared__ float sc[128], sh[128];
    int t = threadIdx.x;
    if (t < 128) {
        float m   = sums[t] * invM;
        float var = fmaxf(sums[128 + t] * invM - m * m, 0.f);
        float s   = gamma[t] * rsqrtf(var + 1e-5f);
        sc[t] = s;
        sh[t] = beta[t] - m * s;
    }
    __syncthreads();
    int total = M * 64;
    for (int idx = blockIdx.x * blockDim.x + t; idx < total;
         idx += gridDim.x * blockDim.x) {
        int c2 = (idx & 63) * 2;
        float2 v = ((const float2*)h)[idx];
        float a = fmaxf(fmaf(v.x, sc[c2 + 0], sh[c2 + 0]), 0.f);
        float b = fmaxf(fmaf(v.y, sc[c2 + 1], sh[c2 + 1]), 0.f);
        outb[idx] = (unsigned int)f2bf(a) | ((unsigned int)f2bf(b) << 16);
    }
}

// ---------------------------------------------------------------- launch ---

extern "C" void kernel_launch(void* const* d_in, const int* in_sizes, int n_in,
                              void* d_out, int out_size, void* d_ws, size_t ws_size,
                              hipStream_t stream) {
    const float* x      = (const float*)d_in[0];
    const int*   ei     = (const int*)d_in[1];
    const float* w1     = (const float*)d_in[2];
    const float* b1     = (const float*)d_in[3];
    const float* w2     = (const float*)d_in[4];
    const float* b2     = (const float*)d_in[5];
    const float* w3     = (const float*)d_in[6];
    const float* b3     = (const float*)d_in[7];
    const float* gamma1 = (const float*)d_in[8];
    const float* beta1  = (const float*)d_in[9];
    const float* gamma2 = (const float*)d_in[10];
    const float* beta2  = (const float*)d_in[11];
    float* out = (float*)d_out;

    const int M = in_sizes[0] / CH;   // 50000 nodes
    const int E = in_sizes[1] / 2;    // 600000 edges
    const int* srcp = ei;
    const int* dstp = ei + E;

    size_t off = 0;
    auto alloc = [&](size_t bytes) {
        void* p = (char*)d_ws + off;
        off += (bytes + 255) & ~(size_t)255;
        return p;
    };
    // zeroed-region first (one memset covers degi|fil|bnsumsA|bnsumsB)
    int*   degi    = (int*)  alloc((size_t)M * 4);
    int*   fil     = (int*)  alloc((size_t)M * 4);
    float* bnsumsA = (float*)alloc(1024);
    float* bnsumsB = (float*)alloc(1024);
    size_t zero_bytes = off;
    unsigned int* PB0 = (unsigned int*)alloc((size_t)M * CH * 2);  // bf16 feat
    unsigned int* PB1 = (unsigned int*)alloc((size_t)M * CH * 2);
    unsigned int* PB2 = (unsigned int*)alloc((size_t)M * CH * 2);
    unsigned int* PB3 = (unsigned int*)alloc((size_t)M * CH * 2);
    unsigned int* PB4 = (unsigned int*)alloc((size_t)M * CH * 2);
    float* H      = (float*)alloc((size_t)M * CH * 4);             // fp32 pre-BN
    int2*  csw    = (int2*) alloc((size_t)E * 8);
    int*   rowptr = (int*)  alloc((size_t)(M + 1) * 4);
    int*   bsum   = (int*)  alloc(4096);
    short* Wt     = (short*)alloc((size_t)9 * CH * CH * 2);        // 9 pieces
    (void)ws_size; (void)n_in; (void)out_size;

    const int nb = (M + 1023) / 1024;
    const int gb = (M + GEMM_BM - 1) / GEMM_BM;
    const int pgrid = (M + 15) / 16;   // 16 nodes per 256-thread block

    // ---- graph setup: degree -> rowptr -> CSR ; weight conversion
    hipMemsetAsync(degi, 0, zero_bytes, stream);
    hist_k<<<(E + 255) / 256, 256, 0, stream>>>(dstp, degi, E);
    scan_partial_k<<<nb, 1024, 0, stream>>>(degi, rowptr, bsum, M);
    scan_add2_k<<<nb, 1024, 0, stream>>>(rowptr, bsum, nb, M);
    fill_k<<<(E + 255) / 256, 256, 0, stream>>>(srcp, dstp, rowptr, fil, degi, csw, E);
    wconv_k<<<(9 * 16384 + 255) / 256, 256, 0, stream>>>(w1, w2, w3, Wt, 9 * 16384);

    // ---- layer 1: H = x @ W1 + b1 (stats fused) ; BN+ReLU -> PB0 (bf16)
    gemm_k<false, true><<<gb, 256, 0, stream>>>(x, nullptr, nullptr, nullptr, nullptr,
                                                Wt, b1, H, bnsumsA, M, 1);
    bnapply_k<<<2048, 256, 0, stream>>>(H, bnsumsA, gamma1, beta1, 1.f / (float)M, PB0, M);

    // ---- layer 2 (K=3): Tx0=PB0, Tx1=PB1, Tx2=PB2 ; BN+ReLU -> PB0
    prop_k<<<pgrid, 256, 0, stream>>>((const uint4*)PB0, rowptr, csw,
                                      (const uint4*)PB0, 1.f, 0.f, (uint4*)PB1, M);
    prop_k<<<pgrid, 256, 0, stream>>>((const uint4*)PB1, rowptr, csw,
                                      (const uint4*)PB0, 2.f, -1.f, (uint4*)PB2, M);
    gemm_k<true, true><<<gb, 256, 0, stream>>>(PB0, PB1, PB2, nullptr, nullptr,
                                               Wt + (1 << 14), b2, H, bnsumsB, M, 3);
    bnapply_k<<<2048, 256, 0, stream>>>(H, bnsumsB, gamma2, beta2, 1.f / (float)M, PB0, M);

    // ---- layer 3 (K=5): Tx0=PB0 ... Tx4=PB4, single nP=5 GEMM -> out
    prop_k<<<pgrid, 256, 0, stream>>>((const uint4*)PB0, rowptr, csw,
                                      (const uint4*)PB0, 1.f, 0.f, (uint4*)PB1, M);
    prop_k<<<pgrid, 256, 0, stream>>>((const uint4*)PB1, rowptr, csw,
                                      (const uint4*)PB0, 2.f, -1.f, (uint4*)PB2, M);
    prop_k<<<pgrid, 256, 0, stream>>>((const uint4*)PB2, rowptr, csw,
                                      (const uint4*)PB1, 2.f, -1.f, (uint4*)PB3, M);
    prop_k<<<pgrid, 256, 0, stream>>>((const uint4*)PB3, rowptr, csw,
                                      (const uint4*)PB2, 2.f, -1.f, (uint4*)PB4, M);
    gemm_k<true, false><<<gb, 256, 0, stream>>>(PB0, PB1, PB2, PB3, PB4,
                                                Wt + (4 << 14), b3, out, nullptr, M, 5);
}